// Round 2
// baseline (1155.879 us; speedup 1.0000x reference)
//
#include <hip/hip_runtime.h>
#include <hip/hip_bf16.h>
#include <math.h>

typedef __hip_bfloat16 bf16;

#define NN 50000
#define NE 800000
#define FIN 500
#define DMAP 128
#define DH 128
#define D2H 256
#define NCLS 40
#define NWT 11
#define WTOT 183336

template <typename A, typename B> struct same_t { static constexpr bool v = false; };
template <typename A> struct same_t<A, A> { static constexpr bool v = true; };
struct XTag {};

__device__ __forceinline__ float loadX(const void* p, size_t i, bool isbf) {
    return isbf ? __bfloat162float(((const bf16*)p)[i]) : ((const float*)p)[i];
}

// -------- dtype detection: bf16-interpret 16KB of x, count wild exponents --------
__global__ void k_detect(const void* __restrict__ x, int* __restrict__ flag) {
    __shared__ int cnt;
    if (threadIdx.x == 0) cnt = 0;
    __syncthreads();
    const unsigned short* p = (const unsigned short*)x;
    int wild = 0;
    for (int i = threadIdx.x; i < 8192; i += 256) {
        unsigned short u = p[i];
        int e = (u >> 7) & 0xFF;
        if (e >= 140 || (e <= 93 && u != 0 && u != 0x8000)) wild++;
    }
    atomicAdd(&cnt, wild);
    __syncthreads();
    if (threadIdx.x == 0) flag[0] = (cnt < 819) ? 1 : 0;  // 1 => inputs are bf16
}

// -------- convert all weight tensors to fp32 in ws --------
struct WConv { const void* src[NWT]; int off[NWT + 1]; };

__global__ void k_convert(WConv wc, const int* __restrict__ flag, float* __restrict__ dst) {
    bool isbf = flag[0] != 0;
    for (int i = blockIdx.x * blockDim.x + threadIdx.x; i < WTOT;
         i += gridDim.x * blockDim.x) {
        int s = 0;
        while (s < NWT - 1 && i >= wc.off[s + 1]) ++s;
        int j = i - wc.off[s];
        dst[i] = isbf ? __bfloat162float(((const bf16*)wc.src[s])[j])
                      : ((const float*)wc.src[s])[j];
    }
}

// ---------------- counting sort of edges by dst ----------------
__global__ void k_count(const int* __restrict__ dst, int* __restrict__ deg) {
    int e = blockIdx.x * blockDim.x + threadIdx.x;
    if (e < NE) atomicAdd(&deg[dst[e]], 1);
}

__global__ void k_scan(const int* __restrict__ deg, int* __restrict__ offs,
                       int* __restrict__ cursor) {
    __shared__ int smem[1024];
    __shared__ int carry;
    if (threadIdx.x == 0) carry = 0;
    __syncthreads();
    for (int base = 0; base < NN; base += 1024) {
        int i = base + threadIdx.x;
        int v = (i < NN) ? deg[i] : 0;
        smem[threadIdx.x] = v;
        __syncthreads();
        for (int off = 1; off < 1024; off <<= 1) {
            int t = (threadIdx.x >= off) ? smem[threadIdx.x - off] : 0;
            __syncthreads();
            smem[threadIdx.x] += t;
            __syncthreads();
        }
        int excl = smem[threadIdx.x] - v;
        if (i < NN) { offs[i] = carry + excl; cursor[i] = carry + excl; }
        __syncthreads();
        if (threadIdx.x == 1023) carry += smem[1023];
        __syncthreads();
    }
    if (threadIdx.x == 0) offs[NN] = carry;
}

__global__ void k_scatter(const int* __restrict__ src, const int* __restrict__ dst,
                          int* __restrict__ cursor, int* __restrict__ ssrc) {
    int e = blockIdx.x * blockDim.x + threadIdx.x;
    if (e < NE) {
        int p = atomicAdd(&cursor[dst[e]], 1);
        ssrc[p] = src[e];
    }
}

// ---------------- mean aggregation: one wave per dst node ----------------
template <int D>
__global__ __launch_bounds__(256) void k_aggregate(
    const float* __restrict__ h, const int* __restrict__ offs,
    const int* __restrict__ ssrc, float* __restrict__ mean) {
    int wid = (blockIdx.x * 256 + threadIdx.x) >> 6;
    int lane = threadIdx.x & 63;
    if (wid >= NN) return;
    int beg = offs[wid], end = offs[wid + 1];
    constexpr int V = D / 64;
    float acc[V];
#pragma unroll
    for (int v = 0; v < V; ++v) acc[v] = 0.f;
    for (int i = beg; i < end; ++i) {
        int s = ssrc[i];
        const float* hp = h + (size_t)s * D + lane * V;
        if constexpr (V == 2) {
            float2 val = *(const float2*)hp;
            acc[0] += val.x; acc[1] += val.y;
        } else {
            float4 val = *(const float4*)hp;
            acc[0] += val.x; acc[1] += val.y; acc[2] += val.z; acc[3] += val.w;
        }
    }
    float inv = 1.f / fmaxf((float)(end - beg), 1.f);
    float* mp = mean + (size_t)wid * D + lane * V;
#pragma unroll
    for (int v = 0; v < V; ++v) mp[v] = acc[v] * inv;
}

// ---------------- tiled fp32 GEMM: C = act(A1@B1 [+ A2@B2] + bias) ----------------
template <typename TA, bool DUAL, bool RELU>
__global__ __launch_bounds__(256) void k_gemm(
    const void* __restrict__ A1, const float* __restrict__ B1,
    const float* __restrict__ A2, const float* __restrict__ B2,
    const float* __restrict__ bias, const int* __restrict__ flag,
    float* __restrict__ C, int M, int K, int Nout) {
    __shared__ float As[16][68];
    __shared__ float Bs[16][64];
    bool isbf = false;
    if constexpr (same_t<TA, XTag>::v) isbf = flag[0] != 0;
    int tid = threadIdx.x;
    int am = tid >> 2, ak = (tid & 3) * 4;
    int bk = tid >> 4, bn = (tid & 15) * 4;
    int ty = tid >> 4, tx = tid & 15;
    int rowBase = blockIdx.x * 64;
    int colBase = blockIdx.y * 64;
    float acc[4][4];
#pragma unroll
    for (int i = 0; i < 4; ++i)
#pragma unroll
        for (int j = 0; j < 4; ++j) acc[i][j] = 0.f;

    const int nPass = DUAL ? 2 : 1;
    for (int pass = 0; pass < nPass; ++pass) {
        const float* Bp = (pass == 0) ? B1 : B2;
        for (int k0 = 0; k0 < K; k0 += 16) {
            int gr = rowBase + am;
#pragma unroll
            for (int i = 0; i < 4; ++i) {
                int gk = k0 + ak + i;
                float v = 0.f;
                if (gr < M && gk < K) {
                    if (pass == 0) {
                        if constexpr (same_t<TA, XTag>::v)
                            v = loadX(A1, (size_t)gr * K + gk, isbf);
                        else
                            v = ((const float*)A1)[(size_t)gr * K + gk];
                    } else {
                        v = A2[(size_t)gr * K + gk];
                    }
                }
                As[ak + i][am] = v;
            }
            int gk = k0 + bk;
#pragma unroll
            for (int i = 0; i < 4; ++i) {
                int gc = colBase + bn + i;
                float v = 0.f;
                if (gk < K && gc < Nout) v = Bp[(size_t)gk * Nout + gc];
                Bs[bk][bn + i] = v;
            }
            __syncthreads();
#pragma unroll
            for (int kk = 0; kk < 16; ++kk) {
                float ra[4], rb[4];
#pragma unroll
                for (int i = 0; i < 4; ++i) ra[i] = As[kk][ty * 4 + i];
#pragma unroll
                for (int j = 0; j < 4; ++j) rb[j] = Bs[kk][tx * 4 + j];
#pragma unroll
                for (int i = 0; i < 4; ++i)
#pragma unroll
                    for (int j = 0; j < 4; ++j) acc[i][j] += ra[i] * rb[j];
            }
            __syncthreads();
        }
    }
#pragma unroll
    for (int i = 0; i < 4; ++i) {
        int r = rowBase + ty * 4 + i;
        if (r >= M) continue;
#pragma unroll
        for (int j = 0; j < 4; ++j) {
            int c = colBase + tx * 4 + j;
            if (c >= Nout) continue;
            float v = acc[i][j] + bias[c];
            if (RELU) v = fmaxf(v, 0.f);
            C[(size_t)r * Nout + c] = v;
        }
    }
}

// ---------------- log_softmax over 40 cols: one wave per row ----------------
__global__ __launch_bounds__(256) void k_logsoftmax(const float* __restrict__ logits,
                                                    const int* __restrict__ flag,
                                                    void* __restrict__ out) {
    int wid = (blockIdx.x * 256 + threadIdx.x) >> 6;
    int lane = threadIdx.x & 63;
    if (wid >= NN) return;
    bool isbf = flag[0] != 0;
    float v = (lane < NCLS) ? logits[(size_t)wid * NCLS + lane] : -INFINITY;
    float m = v;
#pragma unroll
    for (int off = 32; off > 0; off >>= 1) m = fmaxf(m, __shfl_xor(m, off));
    float e = (lane < NCLS) ? expf(v - m) : 0.f;
    float s = e;
#pragma unroll
    for (int off = 32; off > 0; off >>= 1) s += __shfl_xor(s, off);
    float ls = logf(s);
    if (lane < NCLS) {
        float r = v - m - ls;
        size_t idx = (size_t)wid * NCLS + lane;
        if (isbf) ((bf16*)out)[idx] = __float2bfloat16(r);
        else      ((float*)out)[idx] = r;
    }
}

extern "C" void kernel_launch(void* const* d_in, const int* in_sizes, int n_in,
                              void* d_out, int out_size, void* d_ws, size_t ws_size,
                              hipStream_t stream) {
    const void* x    = d_in[0];
    const int*  ei   = (const int*)d_in[1];
    const int*  esrc = ei;        // row 0: src
    const int*  edst = ei + NE;   // row 1: dst

    char* ws = (char*)d_ws;
    float* hA   = (float*)ws; ws += (size_t)NN * 256 * 4;
    float* hB   = (float*)ws; ws += (size_t)NN * 256 * 4;
    float* mean = (float*)ws; ws += (size_t)NN * 256 * 4;
    float* wf   = (float*)ws; ws += (size_t)(WTOT + 8) * 4;
    int* deg    = (int*)ws;   ws += (size_t)NN * 4;
    int* offs   = (int*)ws;   ws += (size_t)(NN + 2) * 4;
    int* cursor = (int*)ws;   ws += (size_t)NN * 4;
    int* ssrc   = (int*)ws;   ws += (size_t)NE * 4;
    int* flag   = (int*)ws;   ws += 16;

    // fp32 weight views inside wf (order: inputs 2..12)
    const int woff[NWT + 1] = {0, 64000, 64128, 80512, 80640, 97024, 129792,
                               130048, 162816, 173056, 173096, WTOT};
    float* W_map = wf + woff[0];
    float* b_map = wf + woff[1];
    float* Wl1   = wf + woff[2];
    float* bl1   = wf + woff[3];
    float* Wr1   = wf + woff[4];
    float* Wl2   = wf + woff[5];
    float* bl2   = wf + woff[6];
    float* Wr2   = wf + woff[7];
    float* Wl3   = wf + woff[8];
    float* bl3   = wf + woff[9];
    float* Wr3   = wf + woff[10];

    // --- dtype detect + weight conversion ---
    k_detect<<<1, 256, 0, stream>>>(x, flag);
    WConv wc;
    for (int i = 0; i < NWT; ++i) wc.src[i] = d_in[2 + i];
    for (int i = 0; i <= NWT; ++i) wc.off[i] = woff[i];
    k_convert<<<360, 256, 0, stream>>>(wc, flag, wf);

    // --- CSR bucketing of edges by dst ---
    hipMemsetAsync(deg, 0, (size_t)NN * 4, stream);
    k_count<<<(NE + 255) / 256, 256, 0, stream>>>(edst, deg);
    k_scan<<<1, 1024, 0, stream>>>(deg, offs, cursor);
    k_scatter<<<(NE + 255) / 256, 256, 0, stream>>>(esrc, edst, cursor, ssrc);

    const int gRows = (NN + 63) / 64;
    const int aggBlocks = (NN * 64) / 256;

    // h0 = x @ W_map + b_map           [NN,128] fp32 in hA
    k_gemm<XTag, false, false><<<dim3(gRows, 2), 256, 0, stream>>>(
        x, W_map, nullptr, nullptr, b_map, flag, hA, NN, FIN, DMAP);

    // layer 1: h1 = relu(mean(h0) @ Wl1 + bl1 + h0 @ Wr1)  -> hB [NN,128]
    k_aggregate<128><<<aggBlocks, 256, 0, stream>>>(hA, offs, ssrc, mean);
    k_gemm<float, true, true><<<dim3(gRows, 2), 256, 0, stream>>>(
        mean, Wl1, hA, Wr1, bl1, flag, hB, NN, DH, DH);

    // layer 2: h2 = relu(mean(h1) @ Wl2 + bl2 + h1 @ Wr2)  -> hA [NN,256]
    k_aggregate<128><<<aggBlocks, 256, 0, stream>>>(hB, offs, ssrc, mean);
    k_gemm<float, true, true><<<dim3(gRows, 4), 256, 0, stream>>>(
        mean, Wl2, hB, Wr2, bl2, flag, hA, NN, DH, D2H);

    // layer 3: logits = mean(h2) @ Wl3 + bl3 + h2 @ Wr3    -> hB [NN,40]
    k_aggregate<256><<<aggBlocks, 256, 0, stream>>>(hA, offs, ssrc, mean);
    k_gemm<float, true, false><<<dim3(gRows, 1), 256, 0, stream>>>(
        mean, Wl3, hA, Wr3, bl3, flag, hB, NN, D2H, NCLS);

    // log_softmax -> out (dtype per flag)
    k_logsoftmax<<<aggBlocks, 256, 0, stream>>>(hB, flag, d_out);
}

// Round 4
// 827.213 us; speedup vs baseline: 1.3973x; 1.3973x over previous
//
#include <hip/hip_runtime.h>
#include <math.h>

#define NN 50000
#define NE 800000
#define FIN 500
#define DH 128
#define D2H 256
#define NCLS 40

typedef short short8 __attribute__((ext_vector_type(8)));
typedef float f32x4 __attribute__((ext_vector_type(4)));

__device__ __forceinline__ unsigned short f2bf(float f) {
    unsigned u = __float_as_uint(f);
    unsigned r = (u + 0x7FFFu + ((u >> 16) & 1u)) >> 16;
    return (unsigned short)r;
}
__device__ __forceinline__ float bf2f(unsigned short h) {
    return __uint_as_float(((unsigned)h) << 16);
}

// ---------------- weight split+transpose: W[K][N] fp32 -> Wt hi/lo [N][Kpad] bf16 ----------------
__global__ void k_wsplit(const float* __restrict__ W, short* __restrict__ dh,
                         short* __restrict__ dl, int K, int N, int kplog) {
    int i = blockIdx.x * 256 + threadIdx.x;
    int Kpad = 1 << kplog;
    if (i >= N * Kpad) return;
    int n = i >> kplog, k = i & (Kpad - 1);
    float v = (k < K) ? W[(size_t)k * N + n] : 0.f;
    unsigned short hi = f2bf(v);
    float lo = v - bf2f(hi);
    dh[i] = (short)hi;
    dl[i] = (short)f2bf(lo);
}

// ---------------- counting sort of edges by dst ----------------
__global__ void k_count(const int* __restrict__ dst, int* __restrict__ deg) {
    int e = blockIdx.x * blockDim.x + threadIdx.x;
    if (e < NE) atomicAdd(&deg[dst[e]], 1);
}

__global__ void k_scan(const int* __restrict__ deg, int* __restrict__ offs,
                       int* __restrict__ cursor) {
    __shared__ int smem[1024];
    __shared__ int carry;
    if (threadIdx.x == 0) carry = 0;
    __syncthreads();
    for (int base = 0; base < NN; base += 1024) {
        int i = base + threadIdx.x;
        int v = (i < NN) ? deg[i] : 0;
        smem[threadIdx.x] = v;
        __syncthreads();
        for (int off = 1; off < 1024; off <<= 1) {
            int t = (threadIdx.x >= off) ? smem[threadIdx.x - off] : 0;
            __syncthreads();
            smem[threadIdx.x] += t;
            __syncthreads();
        }
        int excl = smem[threadIdx.x] - v;
        if (i < NN) { offs[i] = carry + excl; cursor[i] = carry + excl; }
        __syncthreads();
        if (threadIdx.x == 1023) carry += smem[1023];
        __syncthreads();
    }
    if (threadIdx.x == 0) offs[NN] = carry;
}

__global__ void k_scatter(const int* __restrict__ src, const int* __restrict__ dst,
                          int* __restrict__ cursor, int* __restrict__ ssrc) {
    int e = blockIdx.x * blockDim.x + threadIdx.x;
    if (e < NE) {
        int p = atomicAdd(&cursor[dst[e]], 1);
        ssrc[p] = src[e];
    }
}

// ---------------- mean aggregation ----------------
// D=128: one wave per node, 2 edges/iter (half-wave each, float4 lanes)
__global__ __launch_bounds__(256) void k_agg128(
    const float* __restrict__ h, const int* __restrict__ offs,
    const int* __restrict__ ssrc, float* __restrict__ mean) {
    int wid = (blockIdx.x * 256 + threadIdx.x) >> 6;
    int lane = threadIdx.x & 63;
    if (wid >= NN) return;
    int sub = lane >> 5, l32 = lane & 31;
    int beg = offs[wid], end = offs[wid + 1];
    f32x4 acc = {0.f, 0.f, 0.f, 0.f};
    for (int i = beg + sub; i < end; i += 2) {
        int s = ssrc[i];
        f32x4 v = *(const f32x4*)(h + (size_t)s * 128 + l32 * 4);
        acc += v;
    }
    acc[0] += __shfl_xor(acc[0], 32);
    acc[1] += __shfl_xor(acc[1], 32);
    acc[2] += __shfl_xor(acc[2], 32);
    acc[3] += __shfl_xor(acc[3], 32);
    if (sub == 0) {
        float inv = 1.f / fmaxf((float)(end - beg), 1.f);
        acc *= inv;
        *(f32x4*)(mean + (size_t)wid * 128 + l32 * 4) = acc;
    }
}

// D=256: one wave per node, 1 edge/iter, float4 lanes
__global__ __launch_bounds__(256) void k_agg256(
    const float* __restrict__ h, const int* __restrict__ offs,
    const int* __restrict__ ssrc, float* __restrict__ mean) {
    int wid = (blockIdx.x * 256 + threadIdx.x) >> 6;
    int lane = threadIdx.x & 63;
    if (wid >= NN) return;
    int beg = offs[wid], end = offs[wid + 1];
    f32x4 acc = {0.f, 0.f, 0.f, 0.f};
    for (int i = beg; i < end; ++i) {
        int s = ssrc[i];
        f32x4 v = *(const f32x4*)(h + (size_t)s * 256 + lane * 4);
        acc += v;
    }
    float inv = 1.f / fmaxf((float)(end - beg), 1.f);
    acc *= inv;
    *(f32x4*)(mean + (size_t)wid * 256 + lane * 4) = acc;
}

// ---------------- MFMA GEMM with bf16 hi/lo split (fp32-accurate) ----------------
// C[M,N] = act( sum_src A_src @ B_src + bias ),  A fp32 (split on stage),
// B pre-split bf16 hi/lo transposed [N][Kpad].
template <int TM, int BN, int NWM, int NWN, int NSRC, bool RELU>
__global__ __launch_bounds__(256, 2) void k_mm(
    const float* __restrict__ A1, const float* __restrict__ A2,
    const short* __restrict__ B1h, const short* __restrict__ B1l,
    const short* __restrict__ B2h, const short* __restrict__ B2l,
    const float* __restrict__ bias, float* __restrict__ C,
    int M, int N, int K, int Kpad) {
    constexpr int MT = TM / NWM / 16;
    constexpr int NT = BN / NWN / 16;
    __shared__ short Ah[NSRC][TM][32];
    __shared__ short Al[NSRC][TM][32];
    __shared__ short Bh[NSRC][BN][32];
    __shared__ short Bl[NSRC][BN][32];
    int tid = threadIdx.x;
    int wave = tid >> 6, lane = tid & 63;
    int wm = wave / NWN, wn = wave % NWN;
    int quad = lane >> 4, l16 = lane & 15;
    int rowBase = blockIdx.x * TM, colBase = blockIdx.y * BN;

    f32x4 acc[MT][NT];
#pragma unroll
    for (int m = 0; m < MT; ++m)
#pragma unroll
        for (int n = 0; n < NT; ++n) acc[m][n] = (f32x4){0.f, 0.f, 0.f, 0.f};

    const int ATOT = NSRC * TM * 8;      // float4 units
    const int BTOT = NSRC * 2 * BN * 4;  // int4 units (8 shorts each)

    for (int k0 = 0; k0 < Kpad; k0 += 32) {
        __syncthreads();
        // ---- stage A (fp32 -> hi/lo bf16) ----
        for (int q = tid; q < ATOT; q += 256) {
            int src = (NSRC == 2) ? (q >= TM * 8 ? 1 : 0) : 0;
            int rem = q - src * TM * 8;
            int r = rem >> 3, kq = (rem & 7) * 4;
            const float* Ap = (NSRC == 2 && src) ? A2 : A1;
            f32x4 v = {0.f, 0.f, 0.f, 0.f};
            int gr = rowBase + r;
            if (gr < M && (k0 + kq) < K)
                v = *(const f32x4*)(Ap + (size_t)gr * K + k0 + kq);
            short hh[4], ll[4];
#pragma unroll
            for (int j = 0; j < 4; ++j) {
                unsigned short hi = f2bf(v[j]);
                float lo = v[j] - bf2f(hi);
                hh[j] = (short)hi;
                ll[j] = (short)f2bf(lo);
            }
            *(int2*)&Ah[src][r][kq] = *(const int2*)hh;
            *(int2*)&Al[src][r][kq] = *(const int2*)ll;
        }
        // ---- stage B (copy pre-split bf16, transposed layout) ----
        for (int q = tid; q < BTOT; q += 256) {
            int src = q / (2 * BN * 4);
            int rem = q - src * (2 * BN * 4);
            int half = rem / (BN * 4);
            int rem2 = rem - half * (BN * 4);
            int n = rem2 >> 2, j = rem2 & 3;
            const short* Bp;
            if (NSRC == 2 && src) Bp = half ? B2l : B2h;
            else                  Bp = half ? B1l : B1h;
            int4 v = {0, 0, 0, 0};
            int gc = colBase + n;
            if (gc < N)
                v = *(const int4*)(Bp + (size_t)gc * Kpad + k0 + j * 8);
            short* dst = half ? &Bl[src][n][j * 8] : &Bh[src][n][j * 8];
            *(int4*)dst = v;
        }
        __syncthreads();
        // ---- compute: 3 hi/lo combos per source ----
#pragma unroll
        for (int src = 0; src < NSRC; ++src) {
            short8 afh[MT], afl[MT];
#pragma unroll
            for (int m = 0; m < MT; ++m) {
                int r = wm * (TM / NWM) + m * 16 + l16;
                afh[m] = *(const short8*)&Ah[src][r][quad * 8];
                afl[m] = *(const short8*)&Al[src][r][quad * 8];
            }
#pragma unroll
            for (int n = 0; n < NT; ++n) {
                int c = wn * (BN / NWN) + n * 16 + l16;
                short8 bh = *(const short8*)&Bh[src][c][quad * 8];
                short8 bl = *(const short8*)&Bl[src][c][quad * 8];
#pragma unroll
                for (int m = 0; m < MT; ++m) {
                    acc[m][n] = __builtin_amdgcn_mfma_f32_16x16x32_bf16(afh[m], bh, acc[m][n], 0, 0, 0);
                    acc[m][n] = __builtin_amdgcn_mfma_f32_16x16x32_bf16(afh[m], bl, acc[m][n], 0, 0, 0);
                    acc[m][n] = __builtin_amdgcn_mfma_f32_16x16x32_bf16(afl[m], bh, acc[m][n], 0, 0, 0);
                }
            }
        }
    }
    // ---- epilogue: C-layout col=lane&15, row=quad*4+reg ----
#pragma unroll
    for (int m = 0; m < MT; ++m) {
        int gr0 = rowBase + wm * (TM / NWM) + m * 16 + quad * 4;
#pragma unroll
        for (int n = 0; n < NT; ++n) {
            int gc = colBase + wn * (BN / NWN) + n * 16 + l16;
            if (gc >= N) continue;
            float b = bias[gc];
#pragma unroll
            for (int r = 0; r < 4; ++r) {
                int gr = gr0 + r;
                if (gr < M) {
                    float v = acc[m][n][r] + b;
                    if (RELU) v = fmaxf(v, 0.f);
                    C[(size_t)gr * N + gc] = v;
                }
            }
        }
    }
}

// ---------------- log_softmax over 40 cols: one wave per row ----------------
__global__ __launch_bounds__(256) void k_logsoftmax(const float* __restrict__ logits,
                                                    float* __restrict__ out) {
    int wid = (blockIdx.x * 256 + threadIdx.x) >> 6;
    int lane = threadIdx.x & 63;
    if (wid >= NN) return;
    float v = (lane < NCLS) ? logits[(size_t)wid * NCLS + lane] : -INFINITY;
    float m = v;
#pragma unroll
    for (int off = 32; off > 0; off >>= 1) m = fmaxf(m, __shfl_xor(m, off));
    float e = (lane < NCLS) ? expf(v - m) : 0.f;
    float s = e;
#pragma unroll
    for (int off = 32; off > 0; off >>= 1) s += __shfl_xor(s, off);
    float ls = logf(s);
    if (lane < NCLS) out[(size_t)wid * NCLS + lane] = v - m - ls;
}

extern "C" void kernel_launch(void* const* d_in, const int* in_sizes, int n_in,
                              void* d_out, int out_size, void* d_ws, size_t ws_size,
                              hipStream_t stream) {
    const float* x    = (const float*)d_in[0];
    const int*   ei   = (const int*)d_in[1];
    const int*   esrc = ei;        // row 0: src
    const int*   edst = ei + NE;   // row 1: dst
    const float* W_map = (const float*)d_in[2];
    const float* b_map = (const float*)d_in[3];
    const float* Wl1   = (const float*)d_in[4];
    const float* bl1   = (const float*)d_in[5];
    const float* Wr1   = (const float*)d_in[6];
    const float* Wl2   = (const float*)d_in[7];
    const float* bl2   = (const float*)d_in[8];
    const float* Wr2   = (const float*)d_in[9];
    const float* Wl3   = (const float*)d_in[10];
    const float* bl3   = (const float*)d_in[11];
    const float* Wr3   = (const float*)d_in[12];
    float* out = (float*)d_out;

    char* ws = (char*)d_ws;
    float* hA   = (float*)ws; ws += (size_t)NN * 256 * 4;
    float* hB   = (float*)ws; ws += (size_t)NN * 256 * 4;
    float* mean = (float*)ws; ws += (size_t)NN * 256 * 4;
    short* wt   = (short*)ws; ws += (size_t)368640 * 2;
    int* deg    = (int*)ws;   ws += (size_t)NN * 4;
    int* offs   = (int*)ws;   ws += (size_t)(NN + 2) * 4;
    int* cursor = (int*)ws;   ws += (size_t)NN * 4;
    int* ssrc   = (int*)ws;   ws += (size_t)NE * 4;

    // split-weight sub-buffers (offsets in shorts)
    short* m_h  = wt + 0;      short* m_l  = wt + 65536;
    short* l1lh = wt + 131072; short* l1ll = wt + 147456;
    short* l1rh = wt + 163840; short* l1rl = wt + 180224;
    short* l2lh = wt + 196608; short* l2ll = wt + 229376;
    short* l2rh = wt + 262144; short* l2rl = wt + 294912;
    short* l3lh = wt + 327680; short* l3ll = wt + 337920;
    short* l3rh = wt + 348160; short* l3rl = wt + 358400;

    // --- weight split/transpose (tiny) ---
    k_wsplit<<<(128 * 512 + 255) / 256, 256, 0, stream>>>(W_map, m_h, m_l, FIN, 128, 9);
    k_wsplit<<<(128 * 128 + 255) / 256, 256, 0, stream>>>(Wl1, l1lh, l1ll, 128, 128, 7);
    k_wsplit<<<(128 * 128 + 255) / 256, 256, 0, stream>>>(Wr1, l1rh, l1rl, 128, 128, 7);
    k_wsplit<<<(256 * 128 + 255) / 256, 256, 0, stream>>>(Wl2, l2lh, l2ll, 128, 256, 7);
    k_wsplit<<<(256 * 128 + 255) / 256, 256, 0, stream>>>(Wr2, l2rh, l2rl, 128, 256, 7);
    k_wsplit<<<(40 * 256 + 255) / 256, 256, 0, stream>>>(Wl3, l3lh, l3ll, 256, 40, 8);
    k_wsplit<<<(40 * 256 + 255) / 256, 256, 0, stream>>>(Wr3, l3rh, l3rl, 256, 40, 8);

    // --- CSR bucketing of edges by dst ---
    (void)hipMemsetAsync(deg, 0, (size_t)NN * 4, stream);
    k_count<<<(NE + 255) / 256, 256, 0, stream>>>(edst, deg);
    k_scan<<<1, 1024, 0, stream>>>(deg, offs, cursor);
    k_scatter<<<(NE + 255) / 256, 256, 0, stream>>>(esrc, edst, cursor, ssrc);

    const int g128 = (NN + 127) / 128;
    const int aggBlocks = (NN * 64) / 256;

    // h0 = x @ W_map + b_map -> hA [NN,128]
    k_mm<128, 128, 2, 2, 1, false><<<dim3(g128, 1), 256, 0, stream>>>(
        x, nullptr, m_h, m_l, nullptr, nullptr, b_map, hA, NN, 128, FIN, 512);

    // layer 1 -> hB [NN,128]
    k_agg128<<<aggBlocks, 256, 0, stream>>>(hA, offs, ssrc, mean);
    k_mm<128, 128, 2, 2, 2, true><<<dim3(g128, 1), 256, 0, stream>>>(
        mean, hA, l1lh, l1ll, l1rh, l1rl, bl1, hB, NN, DH, DH, DH);

    // layer 2 -> hA [NN,256]
    k_agg128<<<aggBlocks, 256, 0, stream>>>(hB, offs, ssrc, mean);
    k_mm<128, 128, 2, 2, 2, true><<<dim3(g128, 2), 256, 0, stream>>>(
        mean, hB, l2lh, l2ll, l2rh, l2rl, bl2, hA, NN, D2H, DH, DH);

    // layer 3 -> hB [NN,40]
    k_agg256<<<aggBlocks, 256, 0, stream>>>(hA, offs, ssrc, mean);
    k_mm<128, 64, 2, 2, 2, false><<<dim3(g128, 1), 256, 0, stream>>>(
        mean, hA, l3lh, l3ll, l3rh, l3rl, bl3, hB, NN, NCLS, D2H, D2H);

    // log_softmax -> fp32 out
    k_logsoftmax<<<aggBlocks, 256, 0, stream>>>(hB, out);
}

// Round 5
// 654.629 us; speedup vs baseline: 1.7657x; 1.2636x over previous
//
#include <hip/hip_runtime.h>
#include <math.h>

#define NN 50000
#define NE 800000
#define FIN 500
#define DH 128
#define D2H 256
#define NCLS 40
#define NB 196  // scan blocks = ceil(NN/256)

typedef short short8 __attribute__((ext_vector_type(8)));
typedef float f32x4 __attribute__((ext_vector_type(4)));

__device__ __forceinline__ unsigned short f2bf(float f) {
    unsigned u = __float_as_uint(f);
    unsigned r = (u + 0x7FFFu + ((u >> 16) & 1u)) >> 16;
    return (unsigned short)r;
}
__device__ __forceinline__ float bf2f(unsigned short h) {
    return __uint_as_float(((unsigned)h) << 16);
}

// ---------------- weight split+transpose: W[K][N] fp32 -> Wt hi/lo [N][Kpad] bf16 ----------------
__global__ void k_wsplit(const float* __restrict__ W, short* __restrict__ dh,
                         short* __restrict__ dl, int K, int N, int kplog) {
    int i = blockIdx.x * 256 + threadIdx.x;
    int Kpad = 1 << kplog;
    if (i >= N * Kpad) return;
    int n = i >> kplog, k = i & (Kpad - 1);
    float v = (k < K) ? W[(size_t)k * N + n] : 0.f;
    unsigned short hi = f2bf(v);
    float lo = v - bf2f(hi);
    dh[i] = (short)hi;
    dl[i] = (short)f2bf(lo);
}

// ---------------- counting sort of edges by dst ----------------
__global__ void k_count(const int* __restrict__ dst, int* __restrict__ deg) {
    int e = blockIdx.x * blockDim.x + threadIdx.x;
    if (e < NE) atomicAdd(&deg[dst[e]], 1);
}

// two-level scan: block partials -> scan partials -> add
__global__ void k_scan1(const int* __restrict__ deg, int* __restrict__ offs,
                        int* __restrict__ bsum) {
    __shared__ int sm[256];
    int tid = threadIdx.x;
    int i = blockIdx.x * 256 + tid;
    int v = (i < NN) ? deg[i] : 0;
    sm[tid] = v;
    __syncthreads();
    for (int off = 1; off < 256; off <<= 1) {
        int t = (tid >= off) ? sm[tid - off] : 0;
        __syncthreads();
        sm[tid] += t;
        __syncthreads();
    }
    if (i < NN) offs[i] = sm[tid] - v;
    if (tid == 255) bsum[blockIdx.x] = sm[255];
}

__global__ void k_scan2(const int* __restrict__ bsum, int* __restrict__ bpre,
                        int* __restrict__ offs) {
    __shared__ int sm[256];
    int tid = threadIdx.x;
    int v = (tid < NB) ? bsum[tid] : 0;
    sm[tid] = v;
    __syncthreads();
    for (int off = 1; off < 256; off <<= 1) {
        int t = (tid >= off) ? sm[tid - off] : 0;
        __syncthreads();
        sm[tid] += t;
        __syncthreads();
    }
    if (tid < NB) bpre[tid] = sm[tid] - v;
    if (tid == 255) offs[NN] = sm[255];
}

__global__ void k_scan3(int* __restrict__ offs, const int* __restrict__ bpre,
                        int* __restrict__ cursor) {
    int i = blockIdx.x * 256 + threadIdx.x;
    if (i < NN) {
        int v = offs[i] + bpre[blockIdx.x];
        offs[i] = v;
        cursor[i] = v;
    }
}

__global__ void k_scatter(const int* __restrict__ src, const int* __restrict__ dst,
                          int* __restrict__ cursor, int* __restrict__ ssrc) {
    int e = blockIdx.x * blockDim.x + threadIdx.x;
    if (e < NE) {
        int p = atomicAdd(&cursor[dst[e]], 1);
        ssrc[p] = src[e];
    }
}

// ---------------- mean aggregation, D=128 ----------------
// one wave per node; quarter-wave (16 lanes) per edge, 4 edges/step, unroll 2 -> 8 edges/iter
__global__ __launch_bounds__(256) void k_agg128(
    const float* __restrict__ h, const int* __restrict__ offs,
    const int* __restrict__ ssrc, float* __restrict__ mean) {
    int wid = (blockIdx.x * 256 + threadIdx.x) >> 6;
    int lane = threadIdx.x & 63;
    if (wid >= NN) return;
    int sub = lane >> 4, l16 = lane & 15;
    int beg = offs[wid], end = offs[wid + 1];
    f32x4 a0 = {0.f, 0.f, 0.f, 0.f}, a1 = {0.f, 0.f, 0.f, 0.f};
    int i = beg + sub;
    for (; i + 4 < end; i += 8) {
        int s0 = ssrc[i];
        int s1 = ssrc[i + 4];
        const float* p0 = h + (size_t)s0 * 128 + l16 * 8;
        const float* p1 = h + (size_t)s1 * 128 + l16 * 8;
        f32x4 v0 = *(const f32x4*)p0;
        f32x4 v1 = *(const f32x4*)(p0 + 4);
        f32x4 v2 = *(const f32x4*)p1;
        f32x4 v3 = *(const f32x4*)(p1 + 4);
        a0 += v0; a1 += v1; a0 += v2; a1 += v3;
    }
    if (i < end) {
        int s0 = ssrc[i];
        const float* p0 = h + (size_t)s0 * 128 + l16 * 8;
        a0 += *(const f32x4*)p0;
        a1 += *(const f32x4*)(p0 + 4);
    }
#pragma unroll
    for (int j = 0; j < 4; ++j) {
        a0[j] += __shfl_xor(a0[j], 16);
        a0[j] += __shfl_xor(a0[j], 32);
        a1[j] += __shfl_xor(a1[j], 16);
        a1[j] += __shfl_xor(a1[j], 32);
    }
    if (sub == 0) {
        float inv = 1.f / fmaxf((float)(end - beg), 1.f);
        a0 *= inv; a1 *= inv;
        *(f32x4*)(mean + (size_t)wid * 128 + l16 * 8) = a0;
        *(f32x4*)(mean + (size_t)wid * 128 + l16 * 8 + 4) = a1;
    }
}

// ---------------- MFMA GEMM with bf16 hi/lo split (fp32-accurate) ----------------
// [Cp|Cq] = act( sum_src A_src @ B_src + bias ); cols < NCp -> Cp, else Cq.
template <int TM, int BN, int NWM, int NWN, int NSRC, bool RELU>
__global__ __launch_bounds__(256, 2) void k_mm(
    const float* __restrict__ A1, const float* __restrict__ A2,
    const short* __restrict__ B1h, const short* __restrict__ B1l,
    const short* __restrict__ B2h, const short* __restrict__ B2l,
    const float* __restrict__ bias, float* __restrict__ Cp, float* __restrict__ Cq,
    int NCp, int M, int N, int K, int Kpad) {
    constexpr int MT = TM / NWM / 16;
    constexpr int NT = BN / NWN / 16;
    __shared__ short Ah[NSRC][TM][32];
    __shared__ short Al[NSRC][TM][32];
    __shared__ short Bh[NSRC][BN][32];
    __shared__ short Bl[NSRC][BN][32];
    int tid = threadIdx.x;
    int wave = tid >> 6, lane = tid & 63;
    int wm = wave / NWN, wn = wave % NWN;
    int quad = lane >> 4, l16 = lane & 15;
    int rowBase = blockIdx.x * TM, colBase = blockIdx.y * BN;

    f32x4 acc[MT][NT];
#pragma unroll
    for (int m = 0; m < MT; ++m)
#pragma unroll
        for (int n = 0; n < NT; ++n) acc[m][n] = (f32x4){0.f, 0.f, 0.f, 0.f};

    const int ATOT = NSRC * TM * 8;      // float4 units
    const int BTOT = NSRC * 2 * BN * 4;  // int4 units (8 shorts each)

    for (int k0 = 0; k0 < Kpad; k0 += 32) {
        __syncthreads();
        // ---- stage A (fp32 -> hi/lo bf16) ----
        for (int q = tid; q < ATOT; q += 256) {
            int src = (NSRC == 2) ? (q >= TM * 8 ? 1 : 0) : 0;
            int rem = q - src * TM * 8;
            int r = rem >> 3, kq = (rem & 7) * 4;
            const float* Ap = (NSRC == 2 && src) ? A2 : A1;
            f32x4 v = {0.f, 0.f, 0.f, 0.f};
            int gr = rowBase + r;
            if (gr < M && (k0 + kq) < K)
                v = *(const f32x4*)(Ap + (size_t)gr * K + k0 + kq);
            short hh[4], ll[4];
#pragma unroll
            for (int j = 0; j < 4; ++j) {
                unsigned short hi = f2bf(v[j]);
                float lo = v[j] - bf2f(hi);
                hh[j] = (short)hi;
                ll[j] = (short)f2bf(lo);
            }
            *(int2*)&Ah[src][r][kq] = *(const int2*)hh;
            *(int2*)&Al[src][r][kq] = *(const int2*)ll;
        }
        // ---- stage B (copy pre-split bf16, transposed layout) ----
        for (int q = tid; q < BTOT; q += 256) {
            int src = q / (2 * BN * 4);
            int rem = q - src * (2 * BN * 4);
            int half = rem / (BN * 4);
            int rem2 = rem - half * (BN * 4);
            int n = rem2 >> 2, j = rem2 & 3;
            const short* Bp;
            if (NSRC == 2 && src) Bp = half ? B2l : B2h;
            else                  Bp = half ? B1l : B1h;
            int4 v = {0, 0, 0, 0};
            int gc = colBase + n;
            if (gc < N)
                v = *(const int4*)(Bp + (size_t)gc * Kpad + k0 + j * 8);
            short* dst = half ? &Bl[src][n][j * 8] : &Bh[src][n][j * 8];
            *(int4*)dst = v;
        }
        __syncthreads();
        // ---- compute: 3 hi/lo combos per source ----
#pragma unroll
        for (int src = 0; src < NSRC; ++src) {
            short8 afh[MT], afl[MT];
#pragma unroll
            for (int m = 0; m < MT; ++m) {
                int r = wm * (TM / NWM) + m * 16 + l16;
                afh[m] = *(const short8*)&Ah[src][r][quad * 8];
                afl[m] = *(const short8*)&Al[src][r][quad * 8];
            }
#pragma unroll
            for (int n = 0; n < NT; ++n) {
                int c = wn * (BN / NWN) + n * 16 + l16;
                short8 bh = *(const short8*)&Bh[src][c][quad * 8];
                short8 bl = *(const short8*)&Bl[src][c][quad * 8];
#pragma unroll
                for (int m = 0; m < MT; ++m) {
                    acc[m][n] = __builtin_amdgcn_mfma_f32_16x16x32_bf16(afh[m], bh, acc[m][n], 0, 0, 0);
                    acc[m][n] = __builtin_amdgcn_mfma_f32_16x16x32_bf16(afh[m], bl, acc[m][n], 0, 0, 0);
                    acc[m][n] = __builtin_amdgcn_mfma_f32_16x16x32_bf16(afl[m], bh, acc[m][n], 0, 0, 0);
                }
            }
        }
    }
    // ---- epilogue: C-layout col=lane&15, row=quad*4+reg ----
#pragma unroll
    for (int m = 0; m < MT; ++m) {
        int gr0 = rowBase + wm * (TM / NWM) + m * 16 + quad * 4;
#pragma unroll
        for (int n = 0; n < NT; ++n) {
            int gc = colBase + wn * (BN / NWN) + n * 16 + l16;
            if (gc >= N) continue;
            float b = bias ? bias[gc] : 0.f;
#pragma unroll
            for (int r = 0; r < 4; ++r) {
                int gr = gr0 + r;
                if (gr < M) {
                    float v = acc[m][n][r] + b;
                    if (RELU) v = fmaxf(v, 0.f);
                    if (gc < NCp) Cp[(size_t)gr * NCp + gc] = v;
                    else          Cq[(size_t)gr * (N - NCp) + (gc - NCp)] = v;
                }
            }
        }
    }
}

// ---------------- fused layer-3 aggregation + bias + residual + log_softmax ----------------
// logits[i] = mean_j p[j] + bl3 + q[i]; out = log_softmax(logits). One wave per node.
__global__ __launch_bounds__(256) void k_final(
    const float* __restrict__ p, const float* __restrict__ q,
    const int* __restrict__ offs, const int* __restrict__ ssrc,
    const float* __restrict__ bl3, float* __restrict__ out) {
    int wid = (blockIdx.x * 256 + threadIdx.x) >> 6;
    int lane = threadIdx.x & 63;
    if (wid >= NN) return;
    bool act = lane < NCLS;
    int beg = offs[wid], end = offs[wid + 1];
    float a0 = 0.f, a1 = 0.f;
    int i = beg;
    for (; i + 1 < end; i += 2) {
        int s0 = ssrc[i], s1 = ssrc[i + 1];
        a0 += act ? p[(size_t)s0 * NCLS + lane] : 0.f;
        a1 += act ? p[(size_t)s1 * NCLS + lane] : 0.f;
    }
    if (i < end) {
        int s0 = ssrc[i];
        a0 += act ? p[(size_t)s0 * NCLS + lane] : 0.f;
    }
    float inv = 1.f / fmaxf((float)(end - beg), 1.f);
    float v = act ? ((a0 + a1) * inv + bl3[lane] + q[(size_t)wid * NCLS + lane]) : -INFINITY;
    float m = v;
#pragma unroll
    for (int off = 32; off > 0; off >>= 1) m = fmaxf(m, __shfl_xor(m, off));
    float e = act ? expf(v - m) : 0.f;
    float s = e;
#pragma unroll
    for (int off = 32; off > 0; off >>= 1) s += __shfl_xor(s, off);
    float ls = logf(s);
    if (act) out[(size_t)wid * NCLS + lane] = v - m - ls;
}

extern "C" void kernel_launch(void* const* d_in, const int* in_sizes, int n_in,
                              void* d_out, int out_size, void* d_ws, size_t ws_size,
                              hipStream_t stream) {
    const float* x    = (const float*)d_in[0];
    const int*   ei   = (const int*)d_in[1];
    const int*   esrc = ei;        // row 0: src
    const int*   edst = ei + NE;   // row 1: dst
    const float* W_map = (const float*)d_in[2];
    const float* b_map = (const float*)d_in[3];
    const float* Wl1   = (const float*)d_in[4];
    const float* bl1   = (const float*)d_in[5];
    const float* Wr1   = (const float*)d_in[6];
    const float* Wl2   = (const float*)d_in[7];
    const float* bl2   = (const float*)d_in[8];
    const float* Wr2   = (const float*)d_in[9];
    const float* Wl3   = (const float*)d_in[10];
    const float* bl3   = (const float*)d_in[11];
    const float* Wr3   = (const float*)d_in[12];
    float* out = (float*)d_out;

    char* ws = (char*)d_ws;
    float* hA   = (float*)ws; ws += (size_t)NN * 256 * 4;
    float* hB   = (float*)ws; ws += (size_t)NN * 256 * 4;
    float* mean = (float*)ws; ws += (size_t)NN * 256 * 4;
    short* wt   = (short*)ws; ws += (size_t)368640 * 2;
    int* deg    = (int*)ws;   ws += (size_t)NN * 4;
    int* offs   = (int*)ws;   ws += (size_t)(NN + 2) * 4;
    int* cursor = (int*)ws;   ws += (size_t)NN * 4;
    int* ssrc   = (int*)ws;   ws += (size_t)NE * 4;
    int* bsum   = (int*)ws;   ws += (size_t)256 * 4;
    int* bpre   = (int*)ws;   ws += (size_t)256 * 4;

    // split-weight sub-buffers (offsets in shorts)
    short* m_h  = wt + 0;      short* m_l  = wt + 65536;
    short* l1lh = wt + 131072; short* l1ll = wt + 147456;
    short* l1rh = wt + 163840; short* l1rl = wt + 180224;
    short* l2lh = wt + 196608; short* l2ll = wt + 229376;
    short* l2rh = wt + 262144; short* l2rl = wt + 294912;
    short* c3h  = wt + 327680; short* c3l  = wt + 348160;  // [80][256] concat(Wl3,Wr3)

    // --- weight split/transpose (tiny) ---
    k_wsplit<<<(128 * 512 + 255) / 256, 256, 0, stream>>>(W_map, m_h, m_l, FIN, 128, 9);
    k_wsplit<<<(128 * 128 + 255) / 256, 256, 0, stream>>>(Wl1, l1lh, l1ll, 128, 128, 7);
    k_wsplit<<<(128 * 128 + 255) / 256, 256, 0, stream>>>(Wr1, l1rh, l1rl, 128, 128, 7);
    k_wsplit<<<(256 * 128 + 255) / 256, 256, 0, stream>>>(Wl2, l2lh, l2ll, 128, 256, 7);
    k_wsplit<<<(256 * 128 + 255) / 256, 256, 0, stream>>>(Wr2, l2rh, l2rl, 128, 256, 7);
    k_wsplit<<<(40 * 256 + 255) / 256, 256, 0, stream>>>(Wl3, c3h, c3l, 256, 40, 8);
    k_wsplit<<<(40 * 256 + 255) / 256, 256, 0, stream>>>(Wr3, c3h + 40 * 256, c3l + 40 * 256, 256, 40, 8);

    // --- CSR bucketing of edges by dst (two-level scan) ---
    (void)hipMemsetAsync(deg, 0, (size_t)NN * 4, stream);
    k_count<<<(NE + 255) / 256, 256, 0, stream>>>(edst, deg);
    k_scan1<<<NB, 256, 0, stream>>>(deg, offs, bsum);
    k_scan2<<<1, 256, 0, stream>>>(bsum, bpre, offs);
    k_scan3<<<NB, 256, 0, stream>>>(offs, bpre, cursor);
    k_scatter<<<(NE + 255) / 256, 256, 0, stream>>>(esrc, edst, cursor, ssrc);

    const int g128 = (NN + 127) / 128;
    const int aggBlocks = (NN * 64) / 256;

    // h0 = x @ W_map + b_map -> hA [NN,128]
    k_mm<128, 128, 2, 2, 1, false><<<dim3(g128, 1), 256, 0, stream>>>(
        x, nullptr, m_h, m_l, nullptr, nullptr, b_map, hA, nullptr, 128, NN, 128, FIN, 512);

    // layer 1 -> hB [NN,128]
    k_agg128<<<aggBlocks, 256, 0, stream>>>(hA, offs, ssrc, mean);
    k_mm<128, 128, 2, 2, 2, true><<<dim3(g128, 1), 256, 0, stream>>>(
        mean, hA, l1lh, l1ll, l1rh, l1rl, bl1, hB, nullptr, 128, NN, DH, DH, DH);

    // layer 2 -> hA [NN,256]
    k_agg128<<<aggBlocks, 256, 0, stream>>>(hB, offs, ssrc, mean);
    k_mm<128, 128, 2, 2, 2, true><<<dim3(g128, 2), 256, 0, stream>>>(
        mean, hB, l2lh, l2ll, l2rh, l2rl, bl2, hA, nullptr, 256, NN, D2H, DH, DH);

    // layer 3: [p|q] = h2 @ [Wl3|Wr3]  (p -> mean, q -> hB, no bias here)
    k_mm<128, 80, 4, 1, 1, false><<<dim3(g128, 1), 256, 0, stream>>>(
        hA, nullptr, c3h, c3l, nullptr, nullptr, nullptr, mean, hB, NCLS, NN, 80, D2H, D2H);

    // fused: logits = mean_agg(p) + bl3 + q; log_softmax -> out
    k_final<<<aggBlocks, 256, 0, stream>>>(mean, hB, offs, ssrc, bl3, out);
}

// Round 6
// 582.259 us; speedup vs baseline: 1.9852x; 1.1243x over previous
//
#include <hip/hip_runtime.h>
#include <math.h>

#define NN 50000
#define NE 800000
#define FIN 500
#define DH 128
#define D2H 256
#define NCLS 40
#define NB 196  // scan blocks = ceil(NN/256)

typedef short short8 __attribute__((ext_vector_type(8)));
typedef float f32x4 __attribute__((ext_vector_type(4)));

__device__ __forceinline__ unsigned short f2bf(float f) {
    unsigned u = __float_as_uint(f);
    unsigned r = (u + 0x7FFFu + ((u >> 16) & 1u)) >> 16;
    return (unsigned short)r;
}
__device__ __forceinline__ float bf2f(unsigned short h) {
    return __uint_as_float(((unsigned)h) << 16);
}

// ---- weight split+transpose: W[Ksrc][N] fp32 -> dst hi/lo [N][KpadTot] bf16 at col offset koff ----
// writes len (=pow2, 1<<llog) cols per row n; k >= Ksrc zero-filled.
__global__ void k_wsplit(const float* __restrict__ W, short* __restrict__ dh,
                         short* __restrict__ dl, int Ksrc, int N, int KpadTot,
                         int koff, int llog) {
    int i = blockIdx.x * 256 + threadIdx.x;
    int len = 1 << llog;
    if (i >= N * len) return;
    int n = i >> llog, kk = i & (len - 1);
    float v = (kk < Ksrc) ? W[(size_t)kk * N + n] : 0.f;
    unsigned short hi = f2bf(v);
    float lo = v - bf2f(hi);
    size_t di = (size_t)n * KpadTot + koff + kk;
    dh[di] = (short)hi;
    dl[di] = (short)f2bf(lo);
}

// ---------------- counting sort of edges by dst ----------------
__global__ void k_count(const int* __restrict__ dst, int* __restrict__ deg) {
    int e = blockIdx.x * blockDim.x + threadIdx.x;
    if (e < NE) atomicAdd(&deg[dst[e]], 1);
}

__global__ void k_scan1(const int* __restrict__ deg, int* __restrict__ offs,
                        int* __restrict__ bsum) {
    __shared__ int sm[256];
    int tid = threadIdx.x;
    int i = blockIdx.x * 256 + tid;
    int v = (i < NN) ? deg[i] : 0;
    sm[tid] = v;
    __syncthreads();
    for (int off = 1; off < 256; off <<= 1) {
        int t = (tid >= off) ? sm[tid - off] : 0;
        __syncthreads();
        sm[tid] += t;
        __syncthreads();
    }
    if (i < NN) offs[i] = sm[tid] - v;
    if (tid == 255) bsum[blockIdx.x] = sm[255];
}

__global__ void k_scan2(const int* __restrict__ bsum, int* __restrict__ bpre,
                        int* __restrict__ offs) {
    __shared__ int sm[256];
    int tid = threadIdx.x;
    int v = (tid < NB) ? bsum[tid] : 0;
    sm[tid] = v;
    __syncthreads();
    for (int off = 1; off < 256; off <<= 1) {
        int t = (tid >= off) ? sm[tid - off] : 0;
        __syncthreads();
        sm[tid] += t;
        __syncthreads();
    }
    if (tid < NB) bpre[tid] = sm[tid] - v;
    if (tid == 255) offs[NN] = sm[255];
}

__global__ void k_scan3(int* __restrict__ offs, const int* __restrict__ bpre,
                        int* __restrict__ cursor) {
    int i = blockIdx.x * 256 + threadIdx.x;
    if (i < NN) {
        int v = offs[i] + bpre[blockIdx.x];
        offs[i] = v;
        cursor[i] = v;
    }
}

__global__ void k_scatter(const int* __restrict__ src, const int* __restrict__ dst,
                          int* __restrict__ cursor, int* __restrict__ ssrc) {
    int e = blockIdx.x * blockDim.x + threadIdx.x;
    if (e < NE) {
        int p = atomicAdd(&cursor[dst[e]], 1);
        ssrc[p] = src[e];
    }
}

// ---------------- mean aggregation over cols 0..127 of cat[NN][256] -> cols 128..255 ----------------
// one wave per node; quarter-wave (16 lanes) per edge, 4 edges/step, unroll 2
__global__ __launch_bounds__(256) void k_aggcat(
    float* __restrict__ cat, const int* __restrict__ offs,
    const int* __restrict__ ssrc) {
    int wid = (blockIdx.x * 256 + threadIdx.x) >> 6;
    int lane = threadIdx.x & 63;
    if (wid >= NN) return;
    int sub = lane >> 4, l16 = lane & 15;
    int beg = offs[wid], end = offs[wid + 1];
    f32x4 a0 = {0.f, 0.f, 0.f, 0.f}, a1 = {0.f, 0.f, 0.f, 0.f};
    int i = beg + sub;
    for (; i + 4 < end; i += 8) {
        int s0 = ssrc[i];
        int s1 = ssrc[i + 4];
        const float* p0 = cat + (size_t)s0 * 256 + l16 * 8;
        const float* p1 = cat + (size_t)s1 * 256 + l16 * 8;
        f32x4 v0 = *(const f32x4*)p0;
        f32x4 v1 = *(const f32x4*)(p0 + 4);
        f32x4 v2 = *(const f32x4*)p1;
        f32x4 v3 = *(const f32x4*)(p1 + 4);
        a0 += v0; a1 += v1; a0 += v2; a1 += v3;
    }
    if (i < end) {
        int s0 = ssrc[i];
        const float* p0 = cat + (size_t)s0 * 256 + l16 * 8;
        a0 += *(const f32x4*)p0;
        a1 += *(const f32x4*)(p0 + 4);
    }
#pragma unroll
    for (int j = 0; j < 4; ++j) {
        a0[j] += __shfl_xor(a0[j], 16);
        a0[j] += __shfl_xor(a0[j], 32);
        a1[j] += __shfl_xor(a1[j], 16);
        a1[j] += __shfl_xor(a1[j], 32);
    }
    if (sub == 0) {
        float inv = 1.f / fmaxf((float)(end - beg), 1.f);
        a0 *= inv; a1 *= inv;
        *(f32x4*)(cat + (size_t)wid * 256 + 128 + l16 * 8) = a0;
        *(f32x4*)(cat + (size_t)wid * 256 + 128 + l16 * 8 + 4) = a1;
    }
}

// ---------------- MFMA GEMM, bf16 hi/lo split (fp32-accurate), single source ----------------
// C = act(A @ B + bias); A fp32 [M,K] (lda=K), B pre-split [N][Kpad].
// Epilogue: col c < splitN -> C0[r*ld0+c], else C1[r*ld1+c-splitN].
template <int TM, int BN, int NWM, int NWN, bool RELU>
__global__ __launch_bounds__(256, 2) void k_mm(
    const float* __restrict__ A, const short* __restrict__ Bhg,
    const short* __restrict__ Blg, const float* __restrict__ bias,
    float* __restrict__ C0, int ld0, float* __restrict__ C1, int ld1, int splitN,
    int M, int N, int K, int Kpad) {
    constexpr int MT = TM / NWM / 16;
    constexpr int NT = BN / NWN / 16;
    __shared__ short Ah[TM][32];
    __shared__ short Al[TM][32];
    __shared__ short Bh[BN][32];
    __shared__ short Bl[BN][32];
    int tid = threadIdx.x;
    int wave = tid >> 6, lane = tid & 63;
    int wm = wave / NWN, wn = wave % NWN;
    int quad = lane >> 4, l16 = lane & 15;
    int rowBase = blockIdx.x * TM, colBase = blockIdx.y * BN;

    f32x4 acc[MT][NT];
#pragma unroll
    for (int m = 0; m < MT; ++m)
#pragma unroll
        for (int n = 0; n < NT; ++n) acc[m][n] = (f32x4){0.f, 0.f, 0.f, 0.f};

    for (int k0 = 0; k0 < Kpad; k0 += 32) {
        __syncthreads();
        // ---- stage A (fp32 -> hi/lo bf16): TM*8 f32x4 units ----
        for (int q = tid; q < TM * 8; q += 256) {
            int r = q >> 3, kq = (q & 7) * 4;
            f32x4 v = {0.f, 0.f, 0.f, 0.f};
            int gr = rowBase + r;
            if (gr < M && (k0 + kq) < K)
                v = *(const f32x4*)(A + (size_t)gr * K + k0 + kq);
            short hh[4], ll[4];
#pragma unroll
            for (int j = 0; j < 4; ++j) {
                unsigned short hi = f2bf(v[j]);
                float lo = v[j] - bf2f(hi);
                hh[j] = (short)hi;
                ll[j] = (short)f2bf(lo);
            }
            *(int2*)&Ah[r][kq] = *(const int2*)hh;
            *(int2*)&Al[r][kq] = *(const int2*)ll;
        }
        // ---- stage B (pre-split copy): 2*BN*4 int4 units ----
        for (int q = tid; q < 2 * BN * 4; q += 256) {
            int half = q / (BN * 4);
            int rem = q - half * (BN * 4);
            int n = rem >> 2, j = rem & 3;
            const short* Bp = half ? Blg : Bhg;
            int4 v = {0, 0, 0, 0};
            int gc = colBase + n;
            if (gc < N) v = *(const int4*)(Bp + (size_t)gc * Kpad + k0 + j * 8);
            short* dst = half ? &Bl[n][j * 8] : &Bh[n][j * 8];
            *(int4*)dst = v;
        }
        __syncthreads();
        // ---- compute: 3 hi/lo combos ----
        short8 afh[MT], afl[MT];
#pragma unroll
        for (int m = 0; m < MT; ++m) {
            int r = wm * (TM / NWM) + m * 16 + l16;
            afh[m] = *(const short8*)&Ah[r][quad * 8];
            afl[m] = *(const short8*)&Al[r][quad * 8];
        }
#pragma unroll
        for (int n = 0; n < NT; ++n) {
            int c = wn * (BN / NWN) + n * 16 + l16;
            short8 bh = *(const short8*)&Bh[c][quad * 8];
            short8 bl = *(const short8*)&Bl[c][quad * 8];
#pragma unroll
            for (int m = 0; m < MT; ++m) {
                acc[m][n] = __builtin_amdgcn_mfma_f32_16x16x32_bf16(afh[m], bh, acc[m][n], 0, 0, 0);
                acc[m][n] = __builtin_amdgcn_mfma_f32_16x16x32_bf16(afh[m], bl, acc[m][n], 0, 0, 0);
                acc[m][n] = __builtin_amdgcn_mfma_f32_16x16x32_bf16(afl[m], bh, acc[m][n], 0, 0, 0);
            }
        }
    }
    // ---- epilogue: C-layout col=lane&15, row=quad*4+reg ----
#pragma unroll
    for (int m = 0; m < MT; ++m) {
        int gr0 = rowBase + wm * (TM / NWM) + m * 16 + quad * 4;
#pragma unroll
        for (int n = 0; n < NT; ++n) {
            int gc = colBase + wn * (BN / NWN) + n * 16 + l16;
            if (gc >= N) continue;
            float b = bias ? bias[gc] : 0.f;
#pragma unroll
            for (int r = 0; r < 4; ++r) {
                int gr = gr0 + r;
                if (gr < M) {
                    float v = acc[m][n][r] + b;
                    if (RELU) v = fmaxf(v, 0.f);
                    if (gc < splitN) C0[(size_t)gr * ld0 + gc] = v;
                    else             C1[(size_t)gr * ld1 + (gc - splitN)] = v;
                }
            }
        }
    }
}

// ---------------- fused layer-3 aggregation + bias + residual + log_softmax ----------------
__global__ __launch_bounds__(256) void k_final(
    const float* __restrict__ p, const float* __restrict__ q,
    const int* __restrict__ offs, const int* __restrict__ ssrc,
    const float* __restrict__ bl3, float* __restrict__ out) {
    int wid = (blockIdx.x * 256 + threadIdx.x) >> 6;
    int lane = threadIdx.x & 63;
    if (wid >= NN) return;
    bool act = lane < NCLS;
    int beg = offs[wid], end = offs[wid + 1];
    float a0 = 0.f, a1 = 0.f;
    int i = beg;
    for (; i + 1 < end; i += 2) {
        int s0 = ssrc[i], s1 = ssrc[i + 1];
        a0 += act ? p[(size_t)s0 * NCLS + lane] : 0.f;
        a1 += act ? p[(size_t)s1 * NCLS + lane] : 0.f;
    }
    if (i < end) {
        int s0 = ssrc[i];
        a0 += act ? p[(size_t)s0 * NCLS + lane] : 0.f;
    }
    float inv = 1.f / fmaxf((float)(end - beg), 1.f);
    float v = act ? ((a0 + a1) * inv + bl3[lane] + q[(size_t)wid * NCLS + lane]) : -INFINITY;
    float m = v;
#pragma unroll
    for (int off = 32; off > 0; off >>= 1) m = fmaxf(m, __shfl_xor(m, off));
    float e = act ? expf(v - m) : 0.f;
    float s = e;
#pragma unroll
    for (int off = 32; off > 0; off >>= 1) s += __shfl_xor(s, off);
    float ls = logf(s);
    if (act) out[(size_t)wid * NCLS + lane] = v - m - ls;
}

extern "C" void kernel_launch(void* const* d_in, const int* in_sizes, int n_in,
                              void* d_out, int out_size, void* d_ws, size_t ws_size,
                              hipStream_t stream) {
    const float* x    = (const float*)d_in[0];
    const int*   ei   = (const int*)d_in[1];
    const int*   esrc = ei;        // row 0: src
    const int*   edst = ei + NE;   // row 1: dst
    const float* W_map = (const float*)d_in[2];
    const float* b_map = (const float*)d_in[3];
    const float* Wl1   = (const float*)d_in[4];
    const float* bl1   = (const float*)d_in[5];
    const float* Wr1   = (const float*)d_in[6];
    const float* Wl2   = (const float*)d_in[7];
    const float* bl2   = (const float*)d_in[8];
    const float* Wr2   = (const float*)d_in[9];
    const float* Wl3   = (const float*)d_in[10];
    const float* bl3   = (const float*)d_in[11];
    const float* Wr3   = (const float*)d_in[12];
    float* out = (float*)d_out;

    char* ws = (char*)d_ws;
    float* cat1 = (float*)ws; ws += (size_t)NN * 256 * 4;  // [h0 | mean h0]
    float* cat2 = (float*)ws; ws += (size_t)NN * 256 * 4;  // [h1 | mean h1]
    float* h2   = (float*)ws; ws += (size_t)NN * 256 * 4;  // h2
    short* wt   = (short*)ws; ws += (size_t)368640 * 2;
    int* deg    = (int*)ws;   ws += (size_t)NN * 4;
    int* offs   = (int*)ws;   ws += (size_t)(NN + 2) * 4;
    int* cursor = (int*)ws;   ws += (size_t)NN * 4;
    int* ssrc   = (int*)ws;   ws += (size_t)NE * 4;
    int* bsum   = (int*)ws;   ws += (size_t)256 * 4;
    int* bpre   = (int*)ws;   ws += (size_t)256 * 4;

    // p/q reuse cat1 (retired after layer-1 GEMM consumes it)
    float* p = cat1;
    float* q = cat1 + (size_t)NN * NCLS;

    // split-weight sub-buffers (offsets in shorts)
    short* m_h = wt + 0;      short* m_l = wt + 65536;   // [128][512]
    short* b1h = wt + 131072; short* b1l = wt + 163840;  // [128][256] = [Wr1;Wl1]
    short* b2h = wt + 196608; short* b2l = wt + 262144;  // [256][256] = [Wr2;Wl2]
    short* b3h = wt + 327680; short* b3l = wt + 348160;  // [80][256]  = [Wl3|Wr3]

    // --- weight split/transpose (tiny) ---
    k_wsplit<<<(128 * 512 + 255) / 256, 256, 0, stream>>>(W_map, m_h, m_l, FIN, 128, 512, 0, 9);
    k_wsplit<<<(128 * 128 + 255) / 256, 256, 0, stream>>>(Wr1, b1h, b1l, 128, 128, 256, 0, 7);
    k_wsplit<<<(128 * 128 + 255) / 256, 256, 0, stream>>>(Wl1, b1h, b1l, 128, 128, 256, 128, 7);
    k_wsplit<<<(256 * 128 + 255) / 256, 256, 0, stream>>>(Wr2, b2h, b2l, 128, 256, 256, 0, 7);
    k_wsplit<<<(256 * 128 + 255) / 256, 256, 0, stream>>>(Wl2, b2h, b2l, 128, 256, 256, 128, 7);
    k_wsplit<<<(40 * 256 + 255) / 256, 256, 0, stream>>>(Wl3, b3h, b3l, 256, 40, 256, 0, 8);
    k_wsplit<<<(40 * 256 + 255) / 256, 256, 0, stream>>>(Wr3, b3h + 40 * 256, b3l + 40 * 256, 256, 40, 256, 0, 8);

    // --- CSR bucketing of edges by dst (two-level scan) ---
    (void)hipMemsetAsync(deg, 0, (size_t)NN * 4, stream);
    k_count<<<(NE + 255) / 256, 256, 0, stream>>>(edst, deg);
    k_scan1<<<NB, 256, 0, stream>>>(deg, offs, bsum);
    k_scan2<<<1, 256, 0, stream>>>(bsum, bpre, offs);
    k_scan3<<<NB, 256, 0, stream>>>(offs, bpre, cursor);
    k_scatter<<<(NE + 255) / 256, 256, 0, stream>>>(esrc, edst, cursor, ssrc);

    const int g64 = (NN + 63) / 64;  // 782
    const int aggBlocks = (NN * 64) / 256;

    // h0 = x @ W_map + b_map -> cat1 cols 0..127
    k_mm<64, 64, 2, 2, false><<<dim3(g64, 2), 256, 0, stream>>>(
        x, m_h, m_l, b_map, cat1, 256, nullptr, 0, 128, NN, 128, FIN, 512);

    // mean(h0) -> cat1 cols 128..255
    k_aggcat<<<aggBlocks, 256, 0, stream>>>(cat1, offs, ssrc);

    // h1 = relu(cat1 @ [Wr1;Wl1] + bl1) -> cat2 cols 0..127
    k_mm<64, 64, 2, 2, true><<<dim3(g64, 2), 256, 0, stream>>>(
        cat1, b1h, b1l, bl1, cat2, 256, nullptr, 0, 128, NN, 128, 256, 256);

    // mean(h1) -> cat2 cols 128..255
    k_aggcat<<<aggBlocks, 256, 0, stream>>>(cat2, offs, ssrc);

    // h2 = relu(cat2 @ [Wr2;Wl2] + bl2) -> h2 [NN,256]
    k_mm<64, 64, 2, 2, true><<<dim3(g64, 4), 256, 0, stream>>>(
        cat2, b2h, b2l, bl2, h2, 256, nullptr, 0, 256, NN, 256, 256, 256);

    // [p|q] = h2 @ [Wl3|Wr3]  (no bias; bl3 added in k_final)
    k_mm<64, 80, 4, 1, false><<<dim3(g64, 1), 256, 0, stream>>>(
        h2, b3h, b3l, nullptr, p, NCLS, q, NCLS, NCLS, NN, 80, 256, 256);

    // fused: logits = mean_agg(p) + bl3 + q; log_softmax -> out
    k_final<<<aggBlocks, 256, 0, stream>>>(p, q, offs, ssrc, bl3, out);
}

// Round 7
// 564.591 us; speedup vs baseline: 2.0473x; 1.0313x over previous
//
#include <hip/hip_runtime.h>
#include <math.h>

#define NN 50000
#define NE 800000
#define FIN 500
#define DH 128
#define D2H 256
#define NCLS 40
#define NB 196  // scan blocks = ceil(NN/256)

typedef short short8 __attribute__((ext_vector_type(8)));
typedef float f32x4 __attribute__((ext_vector_type(4)));

__device__ __forceinline__ unsigned short f2bf(float f) {
    unsigned u = __float_as_uint(f);
    unsigned r = (u + 0x7FFFu + ((u >> 16) & 1u)) >> 16;
    return (unsigned short)r;
}
__device__ __forceinline__ float bf2f(unsigned short h) {
    return __uint_as_float(((unsigned)h) << 16);
}

// ---- weight split+transpose: W[Ksrc][N] fp32 -> dst hi/lo [N][KpadTot] bf16 at col offset koff ----
__global__ void k_wsplit(const float* __restrict__ W, short* __restrict__ dh,
                         short* __restrict__ dl, int Ksrc, int N, int KpadTot,
                         int koff, int llog) {
    int i = blockIdx.x * 256 + threadIdx.x;
    int len = 1 << llog;
    if (i >= N * len) return;
    int n = i >> llog, kk = i & (len - 1);
    float v = (kk < Ksrc) ? W[(size_t)kk * N + n] : 0.f;
    unsigned short hi = f2bf(v);
    float lo = v - bf2f(hi);
    size_t di = (size_t)n * KpadTot + koff + kk;
    dh[di] = (short)hi;
    dl[di] = (short)f2bf(lo);
}

// ---------------- counting sort of edges by dst ----------------
__global__ void k_count(const int* __restrict__ dst, int* __restrict__ deg) {
    int e = blockIdx.x * blockDim.x + threadIdx.x;
    if (e < NE) atomicAdd(&deg[dst[e]], 1);
}

__global__ void k_scan1(const int* __restrict__ deg, int* __restrict__ offs,
                        int* __restrict__ bsum) {
    __shared__ int sm[256];
    int tid = threadIdx.x;
    int i = blockIdx.x * 256 + tid;
    int v = (i < NN) ? deg[i] : 0;
    sm[tid] = v;
    __syncthreads();
    for (int off = 1; off < 256; off <<= 1) {
        int t = (tid >= off) ? sm[tid - off] : 0;
        __syncthreads();
        sm[tid] += t;
        __syncthreads();
    }
    if (i < NN) offs[i] = sm[tid] - v;
    if (tid == 255) bsum[blockIdx.x] = sm[255];
}

__global__ void k_scan2(const int* __restrict__ bsum, int* __restrict__ bpre,
                        int* __restrict__ offs) {
    __shared__ int sm[256];
    int tid = threadIdx.x;
    int v = (tid < NB) ? bsum[tid] : 0;
    sm[tid] = v;
    __syncthreads();
    for (int off = 1; off < 256; off <<= 1) {
        int t = (tid >= off) ? sm[tid - off] : 0;
        __syncthreads();
        sm[tid] += t;
        __syncthreads();
    }
    if (tid < NB) bpre[tid] = sm[tid] - v;
    if (tid == 255) offs[NN] = sm[255];
}

__global__ void k_scan3(int* __restrict__ offs, const int* __restrict__ bpre,
                        int* __restrict__ cursor) {
    int i = blockIdx.x * 256 + threadIdx.x;
    if (i < NN) {
        int v = offs[i] + bpre[blockIdx.x];
        offs[i] = v;
        cursor[i] = v;
    }
}

__global__ void k_scatter(const int* __restrict__ src, const int* __restrict__ dst,
                          int* __restrict__ cursor, int* __restrict__ ssrc) {
    int e = blockIdx.x * blockDim.x + threadIdx.x;
    if (e < NE) {
        int p = atomicAdd(&cursor[dst[e]], 1);
        ssrc[p] = src[e];
    }
}

// ---------------- mean aggregation from bf16 table [NN][128] -> fp32 cat cols 128..255 ----------------
// one wave per node; quarter-wave (16 lanes, short8=16B each) per edge; 4 edges/step, unroll 2
__global__ __launch_bounds__(256) void k_aggb(
    const short* __restrict__ hb, const int* __restrict__ offs,
    const int* __restrict__ ssrc, float* __restrict__ cat) {
    int wid = (blockIdx.x * 256 + threadIdx.x) >> 6;
    int lane = threadIdx.x & 63;
    if (wid >= NN) return;
    int sub = lane >> 4, l16 = lane & 15;
    int beg = offs[wid], end = offs[wid + 1];
    f32x4 a0 = {0.f, 0.f, 0.f, 0.f}, a1 = {0.f, 0.f, 0.f, 0.f};
    int i = beg + sub;
    for (; i + 4 < end; i += 8) {
        int s0 = ssrc[i];
        int s1 = ssrc[i + 4];
        short8 v0 = *(const short8*)(hb + (size_t)s0 * 128 + l16 * 8);
        short8 v1 = *(const short8*)(hb + (size_t)s1 * 128 + l16 * 8);
#pragma unroll
        for (int j = 0; j < 4; ++j) {
            a0[j] += bf2f((unsigned short)v0[j]) + bf2f((unsigned short)v1[j]);
            a1[j] += bf2f((unsigned short)v0[j + 4]) + bf2f((unsigned short)v1[j + 4]);
        }
    }
    if (i < end) {
        int s0 = ssrc[i];
        short8 v0 = *(const short8*)(hb + (size_t)s0 * 128 + l16 * 8);
#pragma unroll
        for (int j = 0; j < 4; ++j) {
            a0[j] += bf2f((unsigned short)v0[j]);
            a1[j] += bf2f((unsigned short)v0[j + 4]);
        }
    }
#pragma unroll
    for (int j = 0; j < 4; ++j) {
        a0[j] += __shfl_xor(a0[j], 16);
        a0[j] += __shfl_xor(a0[j], 32);
        a1[j] += __shfl_xor(a1[j], 16);
        a1[j] += __shfl_xor(a1[j], 32);
    }
    if (sub == 0) {
        float inv = 1.f / fmaxf((float)(end - beg), 1.f);
        a0 *= inv; a1 *= inv;
        *(f32x4*)(cat + (size_t)wid * 256 + 128 + l16 * 8) = a0;
        *(f32x4*)(cat + (size_t)wid * 256 + 128 + l16 * 8 + 4) = a1;
    }
}

// ---------------- MFMA GEMM, bf16 hi/lo split (fp32-accurate), single source ----------------
// C = act(A @ B + bias); A fp32 [M,K], B pre-split [N][Kpad].
// Epilogue: col c < splitN -> C0[r*ld0+c], else C1[r*ld1+c-splitN].
// If Cb16 != null, cols < 128 additionally stored as bf16 [M][128].
template <int TM, int BN, int NWM, int NWN, bool RELU>
__global__ __launch_bounds__(256, 2) void k_mm(
    const float* __restrict__ A, const short* __restrict__ Bhg,
    const short* __restrict__ Blg, const float* __restrict__ bias,
    float* __restrict__ C0, int ld0, float* __restrict__ C1, int ld1, int splitN,
    short* __restrict__ Cb16,
    int M, int N, int K, int Kpad) {
    constexpr int MT = TM / NWM / 16;
    constexpr int NT = BN / NWN / 16;
    __shared__ short Ah[TM][32];
    __shared__ short Al[TM][32];
    __shared__ short Bh[BN][32];
    __shared__ short Bl[BN][32];
    int tid = threadIdx.x;
    int wave = tid >> 6, lane = tid & 63;
    int wm = wave / NWN, wn = wave % NWN;
    int quad = lane >> 4, l16 = lane & 15;
    int rowBase = blockIdx.x * TM, colBase = blockIdx.y * BN;

    f32x4 acc[MT][NT];
#pragma unroll
    for (int m = 0; m < MT; ++m)
#pragma unroll
        for (int n = 0; n < NT; ++n) acc[m][n] = (f32x4){0.f, 0.f, 0.f, 0.f};

    for (int k0 = 0; k0 < Kpad; k0 += 32) {
        __syncthreads();
        // ---- stage A (fp32 -> hi/lo bf16): TM*8 f32x4 units ----
        for (int q = tid; q < TM * 8; q += 256) {
            int r = q >> 3, kq = (q & 7) * 4;
            f32x4 v = {0.f, 0.f, 0.f, 0.f};
            int gr = rowBase + r;
            if (gr < M && (k0 + kq) < K)
                v = *(const f32x4*)(A + (size_t)gr * K + k0 + kq);
            short hh[4], ll[4];
#pragma unroll
            for (int j = 0; j < 4; ++j) {
                unsigned short hi = f2bf(v[j]);
                float lo = v[j] - bf2f(hi);
                hh[j] = (short)hi;
                ll[j] = (short)f2bf(lo);
            }
            *(int2*)&Ah[r][kq] = *(const int2*)hh;
            *(int2*)&Al[r][kq] = *(const int2*)ll;
        }
        // ---- stage B (pre-split copy): 2*BN*4 int4 units ----
        for (int q = tid; q < 2 * BN * 4; q += 256) {
            int half = q / (BN * 4);
            int rem = q - half * (BN * 4);
            int n = rem >> 2, j = rem & 3;
            const short* Bp = half ? Blg : Bhg;
            int4 v = {0, 0, 0, 0};
            int gc = colBase + n;
            if (gc < N) v = *(const int4*)(Bp + (size_t)gc * Kpad + k0 + j * 8);
            short* dst = half ? &Bl[n][j * 8] : &Bh[n][j * 8];
            *(int4*)dst = v;
        }
        __syncthreads();
        // ---- compute: 3 hi/lo combos ----
        short8 afh[MT], afl[MT];
#pragma unroll
        for (int m = 0; m < MT; ++m) {
            int r = wm * (TM / NWM) + m * 16 + l16;
            afh[m] = *(const short8*)&Ah[r][quad * 8];
            afl[m] = *(const short8*)&Al[r][quad * 8];
        }
#pragma unroll
        for (int n = 0; n < NT; ++n) {
            int c = wn * (BN / NWN) + n * 16 + l16;
            short8 bh = *(const short8*)&Bh[c][quad * 8];
            short8 bl = *(const short8*)&Bl[c][quad * 8];
#pragma unroll
            for (int m = 0; m < MT; ++m) {
                acc[m][n] = __builtin_amdgcn_mfma_f32_16x16x32_bf16(afh[m], bh, acc[m][n], 0, 0, 0);
                acc[m][n] = __builtin_amdgcn_mfma_f32_16x16x32_bf16(afh[m], bl, acc[m][n], 0, 0, 0);
                acc[m][n] = __builtin_amdgcn_mfma_f32_16x16x32_bf16(afl[m], bh, acc[m][n], 0, 0, 0);
            }
        }
    }
    // ---- epilogue: C-layout col=lane&15, row=quad*4+reg ----
#pragma unroll
    for (int m = 0; m < MT; ++m) {
        int gr0 = rowBase + wm * (TM / NWM) + m * 16 + quad * 4;
#pragma unroll
        for (int n = 0; n < NT; ++n) {
            int gc = colBase + wn * (BN / NWN) + n * 16 + l16;
            if (gc >= N) continue;
            float b = bias ? bias[gc] : 0.f;
#pragma unroll
            for (int r = 0; r < 4; ++r) {
                int gr = gr0 + r;
                if (gr < M) {
                    float v = acc[m][n][r] + b;
                    if (RELU) v = fmaxf(v, 0.f);
                    if (gc < splitN) C0[(size_t)gr * ld0 + gc] = v;
                    else             C1[(size_t)gr * ld1 + (gc - splitN)] = v;
                    if (Cb16 && gc < 128) Cb16[(size_t)gr * 128 + gc] = (short)f2bf(v);
                }
            }
        }
    }
}

// ---------------- fused layer-3 aggregation + bias + residual + log_softmax ----------------
__global__ __launch_bounds__(256) void k_final(
    const float* __restrict__ p, const float* __restrict__ q,
    const int* __restrict__ offs, const int* __restrict__ ssrc,
    const float* __restrict__ bl3, float* __restrict__ out) {
    int wid = (blockIdx.x * 256 + threadIdx.x) >> 6;
    int lane = threadIdx.x & 63;
    if (wid >= NN) return;
    bool act = lane < NCLS;
    int beg = offs[wid], end = offs[wid + 1];
    float a0 = 0.f, a1 = 0.f;
    int i = beg;
    for (; i + 1 < end; i += 2) {
        int s0 = ssrc[i], s1 = ssrc[i + 1];
        a0 += act ? p[(size_t)s0 * NCLS + lane] : 0.f;
        a1 += act ? p[(size_t)s1 * NCLS + lane] : 0.f;
    }
    if (i < end) {
        int s0 = ssrc[i];
        a0 += act ? p[(size_t)s0 * NCLS + lane] : 0.f;
    }
    float inv = 1.f / fmaxf((float)(end - beg), 1.f);
    float v = act ? ((a0 + a1) * inv + bl3[lane] + q[(size_t)wid * NCLS + lane]) : -INFINITY;
    float m = v;
#pragma unroll
    for (int off = 32; off > 0; off >>= 1) m = fmaxf(m, __shfl_xor(m, off));
    float e = act ? expf(v - m) : 0.f;
    float s = e;
#pragma unroll
    for (int off = 32; off > 0; off >>= 1) s += __shfl_xor(s, off);
    float ls = logf(s);
    if (act) out[(size_t)wid * NCLS + lane] = v - m - ls;
}

extern "C" void kernel_launch(void* const* d_in, const int* in_sizes, int n_in,
                              void* d_out, int out_size, void* d_ws, size_t ws_size,
                              hipStream_t stream) {
    const float* x    = (const float*)d_in[0];
    const int*   ei   = (const int*)d_in[1];
    const int*   esrc = ei;        // row 0: src
    const int*   edst = ei + NE;   // row 1: dst
    const float* W_map = (const float*)d_in[2];
    const float* b_map = (const float*)d_in[3];
    const float* Wl1   = (const float*)d_in[4];
    const float* bl1   = (const float*)d_in[5];
    const float* Wr1   = (const float*)d_in[6];
    const float* Wl2   = (const float*)d_in[7];
    const float* bl2   = (const float*)d_in[8];
    const float* Wr2   = (const float*)d_in[9];
    const float* Wl3   = (const float*)d_in[10];
    const float* bl3   = (const float*)d_in[11];
    const float* Wr3   = (const float*)d_in[12];
    float* out = (float*)d_out;

    char* ws = (char*)d_ws;
    float* cat1 = (float*)ws; ws += (size_t)NN * 256 * 4;  // [h0 | mean h0]
    float* cat2 = (float*)ws; ws += (size_t)NN * 256 * 4;  // [h1 | mean h1]
    float* h2   = (float*)ws; ws += (size_t)NN * 256 * 4;  // h2
    short* hb0  = (short*)ws; ws += (size_t)NN * 128 * 2;  // bf16 h0 gather table
    short* hb1  = (short*)ws; ws += (size_t)NN * 128 * 2;  // bf16 h1 gather table
    short* wt   = (short*)ws; ws += (size_t)368640 * 2;
    int* deg    = (int*)ws;   ws += (size_t)NN * 4;
    int* offs   = (int*)ws;   ws += (size_t)(NN + 2) * 4;
    int* cursor = (int*)ws;   ws += (size_t)NN * 4;
    int* ssrc   = (int*)ws;   ws += (size_t)NE * 4;
    int* bsum   = (int*)ws;   ws += (size_t)256 * 4;
    int* bpre   = (int*)ws;   ws += (size_t)256 * 4;

    // p/q reuse cat1 (retired after layer-1 GEMM consumes it)
    float* p = cat1;
    float* q = cat1 + (size_t)NN * NCLS;

    // split-weight sub-buffers (offsets in shorts)
    short* m_h = wt + 0;      short* m_l = wt + 65536;   // [128][512]
    short* b1h = wt + 131072; short* b1l = wt + 163840;  // [128][256] = [Wr1;Wl1]
    short* b2h = wt + 196608; short* b2l = wt + 262144;  // [256][256] = [Wr2;Wl2]
    short* b3h = wt + 327680; short* b3l = wt + 348160;  // [80][256]  = [Wl3|Wr3]

    // --- weight split/transpose (tiny) ---
    k_wsplit<<<(128 * 512 + 255) / 256, 256, 0, stream>>>(W_map, m_h, m_l, FIN, 128, 512, 0, 9);
    k_wsplit<<<(128 * 128 + 255) / 256, 256, 0, stream>>>(Wr1, b1h, b1l, 128, 128, 256, 0, 7);
    k_wsplit<<<(128 * 128 + 255) / 256, 256, 0, stream>>>(Wl1, b1h, b1l, 128, 128, 256, 128, 7);
    k_wsplit<<<(256 * 128 + 255) / 256, 256, 0, stream>>>(Wr2, b2h, b2l, 128, 256, 256, 0, 7);
    k_wsplit<<<(256 * 128 + 255) / 256, 256, 0, stream>>>(Wl2, b2h, b2l, 128, 256, 256, 128, 7);
    k_wsplit<<<(40 * 256 + 255) / 256, 256, 0, stream>>>(Wl3, b3h, b3l, 256, 40, 256, 0, 8);
    k_wsplit<<<(40 * 256 + 255) / 256, 256, 0, stream>>>(Wr3, b3h + 40 * 256, b3l + 40 * 256, 256, 40, 256, 0, 8);

    // --- CSR bucketing of edges by dst (two-level scan) ---
    (void)hipMemsetAsync(deg, 0, (size_t)NN * 4, stream);
    k_count<<<(NE + 255) / 256, 256, 0, stream>>>(edst, deg);
    k_scan1<<<NB, 256, 0, stream>>>(deg, offs, bsum);
    k_scan2<<<1, 256, 0, stream>>>(bsum, bpre, offs);
    k_scan3<<<NB, 256, 0, stream>>>(offs, bpre, cursor);
    k_scatter<<<(NE + 255) / 256, 256, 0, stream>>>(esrc, edst, cursor, ssrc);

    const int g64 = (NN + 63) / 64;  // 782
    const int aggBlocks = (NN * 64) / 256;

    // h0 = x @ W_map + b_map -> cat1 cols 0..127 (+ bf16 copy hb0), single column pass
    k_mm<64, 128, 2, 2, false><<<dim3(g64, 1), 256, 0, stream>>>(
        x, m_h, m_l, b_map, cat1, 256, nullptr, 0, 128, hb0, NN, 128, FIN, 512);

    // mean(h0) from hb0 -> cat1 cols 128..255
    k_aggb<<<aggBlocks, 256, 0, stream>>>(hb0, offs, ssrc, cat1);

    // h1 = relu(cat1 @ [Wr1;Wl1] + bl1) -> cat2 cols 0..127 (+ bf16 copy hb1)
    k_mm<64, 128, 2, 2, true><<<dim3(g64, 1), 256, 0, stream>>>(
        cat1, b1h, b1l, bl1, cat2, 256, nullptr, 0, 128, hb1, NN, 128, 256, 256);

    // mean(h1) from hb1 -> cat2 cols 128..255
    k_aggb<<<aggBlocks, 256, 0, stream>>>(hb1, offs, ssrc, cat2);

    // h2 = relu(cat2 @ [Wr2;Wl2] + bl2) -> h2 [NN,256]
    k_mm<64, 128, 2, 2, true><<<dim3(g64, 2), 256, 0, stream>>>(
        cat2, b2h, b2l, bl2, h2, 256, nullptr, 0, 256, nullptr, NN, 256, 256, 256);

    // [p|q] = h2 @ [Wl3|Wr3]  (no bias; bl3 added in k_final)
    k_mm<64, 80, 4, 1, false><<<dim3(g64, 1), 256, 0, stream>>>(
        h2, b3h, b3l, nullptr, p, NCLS, q, NCLS, NCLS, nullptr, NN, 80, 256, 256);

    // fused: logits = mean_agg(p) + bl3 + q; log_softmax -> out
    k_final<<<aggBlocks, 256, 0, stream>>>(p, q, offs, ssrc, bl3, out);
}

// Round 8
// 532.667 us; speedup vs baseline: 2.1700x; 1.0599x over previous
//
#include <hip/hip_runtime.h>
#include <math.h>

#define NN 50000
#define NE 800000
#define FIN 500
#define DH 128
#define D2H 256
#define NCLS 40
#define NB 196  // scan blocks = ceil(NN/256)

typedef short short8 __attribute__((ext_vector_type(8)));
typedef float f32x4 __attribute__((ext_vector_type(4)));

__device__ __forceinline__ unsigned short f2bf(float f) {
    unsigned u = __float_as_uint(f);
    unsigned r = (u + 0x7FFFu + ((u >> 16) & 1u)) >> 16;
    return (unsigned short)r;
}
__device__ __forceinline__ float bf2f(unsigned short h) {
    return __uint_as_float(((unsigned)h) << 16);
}

// ---- weight split+transpose: W[Ksrc][N] fp32 -> dst hi/lo [N][KpadTot] bf16 at col offset koff ----
__global__ void k_wsplit(const float* __restrict__ W, short* __restrict__ dh,
                         short* __restrict__ dl, int Ksrc, int N, int KpadTot,
                         int koff, int llog) {
    int i = blockIdx.x * 256 + threadIdx.x;
    int len = 1 << llog;
    if (i >= N * len) return;
    int n = i >> llog, kk = i & (len - 1);
    float v = (kk < Ksrc) ? W[(size_t)kk * N + n] : 0.f;
    unsigned short hi = f2bf(v);
    float lo = v - bf2f(hi);
    size_t di = (size_t)n * KpadTot + koff + kk;
    dh[di] = (short)hi;
    dl[di] = (short)f2bf(lo);
}

// ---------------- counting sort of edges by dst ----------------
__global__ void k_count(const int* __restrict__ dst, int* __restrict__ deg) {
    int e = blockIdx.x * blockDim.x + threadIdx.x;
    if (e < NE) atomicAdd(&deg[dst[e]], 1);
}

__global__ void k_scan1(const int* __restrict__ deg, int* __restrict__ offs,
                        int* __restrict__ bsum) {
    __shared__ int sm[256];
    int tid = threadIdx.x;
    int i = blockIdx.x * 256 + tid;
    int v = (i < NN) ? deg[i] : 0;
    sm[tid] = v;
    __syncthreads();
    for (int off = 1; off < 256; off <<= 1) {
        int t = (tid >= off) ? sm[tid - off] : 0;
        __syncthreads();
        sm[tid] += t;
        __syncthreads();
    }
    if (i < NN) offs[i] = sm[tid] - v;
    if (tid == 255) bsum[blockIdx.x] = sm[255];
}

__global__ void k_scan2(const int* __restrict__ bsum, int* __restrict__ bpre,
                        int* __restrict__ offs) {
    __shared__ int sm[256];
    int tid = threadIdx.x;
    int v = (tid < NB) ? bsum[tid] : 0;
    sm[tid] = v;
    __syncthreads();
    for (int off = 1; off < 256; off <<= 1) {
        int t = (tid >= off) ? sm[tid - off] : 0;
        __syncthreads();
        sm[tid] += t;
        __syncthreads();
    }
    if (tid < NB) bpre[tid] = sm[tid] - v;
    if (tid == 255) offs[NN] = sm[255];
}

__global__ void k_scan3(int* __restrict__ offs, const int* __restrict__ bpre,
                        int* __restrict__ cursor) {
    int i = blockIdx.x * 256 + threadIdx.x;
    if (i < NN) {
        int v = offs[i] + bpre[blockIdx.x];
        offs[i] = v;
        cursor[i] = v;
    }
}

__global__ void k_scatter(const int* __restrict__ src, const int* __restrict__ dst,
                          int* __restrict__ cursor, int* __restrict__ ssrc) {
    int e = blockIdx.x * blockDim.x + threadIdx.x;
    if (e < NE) {
        int p = atomicAdd(&cursor[dst[e]], 1);
        ssrc[p] = src[e];
    }
}

// ---- mean aggregation from bf16 hi table [NN][128] -> split hi/lo mean planes [NN][128] ----
// one wave per node; quarter-wave (16 lanes, short8=16B each) per edge; 4 edges/step, unroll 2
__global__ __launch_bounds__(256) void k_aggb(
    const short* __restrict__ hb, const int* __restrict__ offs,
    const int* __restrict__ ssrc, short* __restrict__ mH, short* __restrict__ mL) {
    int wid = (blockIdx.x * 256 + threadIdx.x) >> 6;
    int lane = threadIdx.x & 63;
    if (wid >= NN) return;
    int sub = lane >> 4, l16 = lane & 15;
    int beg = offs[wid], end = offs[wid + 1];
    f32x4 a0 = {0.f, 0.f, 0.f, 0.f}, a1 = {0.f, 0.f, 0.f, 0.f};
    int i = beg + sub;
    for (; i + 4 < end; i += 8) {
        int s0 = ssrc[i];
        int s1 = ssrc[i + 4];
        short8 v0 = *(const short8*)(hb + (size_t)s0 * 128 + l16 * 8);
        short8 v1 = *(const short8*)(hb + (size_t)s1 * 128 + l16 * 8);
#pragma unroll
        for (int j = 0; j < 4; ++j) {
            a0[j] += bf2f((unsigned short)v0[j]) + bf2f((unsigned short)v1[j]);
            a1[j] += bf2f((unsigned short)v0[j + 4]) + bf2f((unsigned short)v1[j + 4]);
        }
    }
    if (i < end) {
        int s0 = ssrc[i];
        short8 v0 = *(const short8*)(hb + (size_t)s0 * 128 + l16 * 8);
#pragma unroll
        for (int j = 0; j < 4; ++j) {
            a0[j] += bf2f((unsigned short)v0[j]);
            a1[j] += bf2f((unsigned short)v0[j + 4]);
        }
    }
#pragma unroll
    for (int j = 0; j < 4; ++j) {
        a0[j] += __shfl_xor(a0[j], 16);
        a0[j] += __shfl_xor(a0[j], 32);
        a1[j] += __shfl_xor(a1[j], 16);
        a1[j] += __shfl_xor(a1[j], 32);
    }
    if (sub == 0) {
        float inv = 1.f / fmaxf((float)(end - beg), 1.f);
        a0 *= inv; a1 *= inv;
        short8 hv, lv;
#pragma unroll
        for (int j = 0; j < 4; ++j) {
            unsigned short h0 = f2bf(a0[j]);
            hv[j] = (short)h0; lv[j] = (short)f2bf(a0[j] - bf2f(h0));
            unsigned short h1 = f2bf(a1[j]);
            hv[j + 4] = (short)h1; lv[j + 4] = (short)f2bf(a1[j] - bf2f(h1));
        }
        *(short8*)(mH + (size_t)wid * 128 + l16 * 8) = hv;
        *(short8*)(mL + (size_t)wid * 128 + l16 * 8) = lv;
    }
}

// ---------------- MFMA GEMM, bf16 hi/lo split (fp32-accurate) ----------------
// TM=64 rows/block, BN cols/block, 4 waves. A: either fp32 [M,K] (AFP32) or two
// pre-split K-segments of hi/lo bf16 planes (seg0 width KS0, seg1 width K-KS0).
// B pre-split [N][Kpad]. Register-prefetch pipeline; LDS rows padded to 40 shorts.
// Output: if CH: bf16 hi/lo planes [M][ldc]; if F0: fp32, col<splitN->F0 else F1.
template <int BN, int NWM, int NWN, bool AFP32, bool RELU>
__global__ __launch_bounds__(256, 4) void k_mm(
    const void* __restrict__ A0hv, const void* __restrict__ A0lv,
    const short* __restrict__ A1h, const short* __restrict__ A1l, int KS0,
    const short* __restrict__ Bhg, const short* __restrict__ Blg,
    const float* __restrict__ bias,
    short* __restrict__ CH, short* __restrict__ CL, int ldc,
    float* __restrict__ F0, float* __restrict__ F1, int splitN,
    int M, int N, int K, int Kpad) {
    constexpr int MT = 64 / NWM / 16;
    constexpr int NT = BN / NWN / 16;
    constexpr int BU = (BN * 4 + 255) / 256;
    __shared__ short Ah[64][40];
    __shared__ short Al[64][40];
    __shared__ short Bh[BN][40];
    __shared__ short Bl[BN][40];
    int tid = threadIdx.x;
    int wave = tid >> 6, lane = tid & 63;
    int wm = wave / NWN, wn = wave % NWN;
    int quad = lane >> 4, l16 = lane & 15;
    int rowBase = blockIdx.x * 64, colBase = blockIdx.y * BN;

    f32x4 acc[MT][NT];
#pragma unroll
    for (int m = 0; m < MT; ++m)
#pragma unroll
        for (int n = 0; n < NT; ++n) acc[m][n] = (f32x4){0.f, 0.f, 0.f, 0.f};

    int4 ra0, ra1, rb0[BU], rb1[BU];
    f32x4 fa0, fa1;

    auto loadTile = [&](int k0) {
#pragma unroll
        for (int u = 0; u < BU; ++u) {
            int q = tid + u * 256;
            rb0[u] = (int4){0, 0, 0, 0};
            rb1[u] = (int4){0, 0, 0, 0};
            if (q < BN * 4) {
                int r = q >> 2, j = q & 3;
                int gc = colBase + r;
                if (gc < N) {
                    rb0[u] = *(const int4*)(Bhg + (size_t)gc * Kpad + k0 + j * 8);
                    rb1[u] = *(const int4*)(Blg + (size_t)gc * Kpad + k0 + j * 8);
                }
            }
        }
        if constexpr (AFP32) {
            const float* A = (const float*)A0hv;
            fa0 = (f32x4){0.f, 0.f, 0.f, 0.f};
            fa1 = (f32x4){0.f, 0.f, 0.f, 0.f};
            int r0 = tid >> 3, c0 = (tid & 7) * 4;
            int gr0 = rowBase + r0;
            if (gr0 < M && (k0 + c0) < K) fa0 = *(const f32x4*)(A + (size_t)gr0 * K + k0 + c0);
            int q1 = tid + 256;
            int r1 = q1 >> 3, c1 = (q1 & 7) * 4;
            int gr1 = rowBase + r1;
            if (gr1 < M && (k0 + c1) < K) fa1 = *(const f32x4*)(A + (size_t)gr1 * K + k0 + c1);
        } else {
            int seg = (k0 >= KS0) ? 1 : 0;
            int segW = seg ? (K - KS0) : KS0;
            const short* ah = seg ? A1h : (const short*)A0hv;
            const short* al = seg ? A1l : (const short*)A0lv;
            int col = k0 - (seg ? KS0 : 0);
            int r = tid >> 2, j = tid & 3;
            int gr = rowBase + r;
            ra0 = (int4){0, 0, 0, 0};
            ra1 = (int4){0, 0, 0, 0};
            if (gr < M) {
                ra0 = *(const int4*)(ah + (size_t)gr * segW + col + j * 8);
                ra1 = *(const int4*)(al + (size_t)gr * segW + col + j * 8);
            }
        }
    };
    auto storeTile = [&]() {
#pragma unroll
        for (int u = 0; u < BU; ++u) {
            int q = tid + u * 256;
            if (q < BN * 4) {
                int r = q >> 2, j = q & 3;
                *(int4*)&Bh[r][j * 8] = rb0[u];
                *(int4*)&Bl[r][j * 8] = rb1[u];
            }
        }
        if constexpr (AFP32) {
            short hh[4], ll[4];
            int r0 = tid >> 3, c0 = (tid & 7) * 4;
#pragma unroll
            for (int j = 0; j < 4; ++j) {
                unsigned short h = f2bf(fa0[j]);
                hh[j] = (short)h; ll[j] = (short)f2bf(fa0[j] - bf2f(h));
            }
            *(int2*)&Ah[r0][c0] = *(const int2*)hh;
            *(int2*)&Al[r0][c0] = *(const int2*)ll;
            int q1 = tid + 256;
            int r1 = q1 >> 3, c1 = (q1 & 7) * 4;
#pragma unroll
            for (int j = 0; j < 4; ++j) {
                unsigned short h = f2bf(fa1[j]);
                hh[j] = (short)h; ll[j] = (short)f2bf(fa1[j] - bf2f(h));
            }
            *(int2*)&Ah[r1][c1] = *(const int2*)hh;
            *(int2*)&Al[r1][c1] = *(const int2*)ll;
        } else {
            int r = tid >> 2, j = tid & 3;
            *(int4*)&Ah[r][j * 8] = ra0;
            *(int4*)&Al[r][j * 8] = ra1;
        }
    };

    loadTile(0);
    for (int k0 = 0; k0 < Kpad; k0 += 32) {
        __syncthreads();
        storeTile();
        __syncthreads();
        if (k0 + 32 < Kpad) loadTile(k0 + 32);
        short8 afh[MT], afl[MT];
#pragma unroll
        for (int m = 0; m < MT; ++m) {
            int r = wm * (64 / NWM) + m * 16 + l16;
            afh[m] = *(const short8*)&Ah[r][quad * 8];
            afl[m] = *(const short8*)&Al[r][quad * 8];
        }
#pragma unroll
        for (int n = 0; n < NT; ++n) {
            int c = wn * (BN / NWN) + n * 16 + l16;
            short8 bh = *(const short8*)&Bh[c][quad * 8];
            short8 bl = *(const short8*)&Bl[c][quad * 8];
#pragma unroll
            for (int m = 0; m < MT; ++m) {
                acc[m][n] = __builtin_amdgcn_mfma_f32_16x16x32_bf16(afh[m], bh, acc[m][n], 0, 0, 0);
                acc[m][n] = __builtin_amdgcn_mfma_f32_16x16x32_bf16(afh[m], bl, acc[m][n], 0, 0, 0);
                acc[m][n] = __builtin_amdgcn_mfma_f32_16x16x32_bf16(afl[m], bh, acc[m][n], 0, 0, 0);
            }
        }
    }
    // ---- epilogue: C-layout col=lane&15, row=quad*4+reg ----
#pragma unroll
    for (int m = 0; m < MT; ++m) {
        int gr0 = rowBase + wm * (64 / NWM) + m * 16 + quad * 4;
#pragma unroll
        for (int n = 0; n < NT; ++n) {
            int gc = colBase + wn * (BN / NWN) + n * 16 + l16;
            if (gc >= N) continue;
            float b = bias ? bias[gc] : 0.f;
#pragma unroll
            for (int r = 0; r < 4; ++r) {
                int gr = gr0 + r;
                if (gr < M) {
                    float v = acc[m][n][r] + b;
                    if (RELU) v = fmaxf(v, 0.f);
                    if (CH) {
                        unsigned short h = f2bf(v);
                        CH[(size_t)gr * ldc + gc] = (short)h;
                        CL[(size_t)gr * ldc + gc] = (short)f2bf(v - bf2f(h));
                    }
                    if (F0) {
                        if (gc < splitN) F0[(size_t)gr * splitN + gc] = v;
                        else             F1[(size_t)gr * (N - splitN) + (gc - splitN)] = v;
                    }
                }
            }
        }
    }
}

// ---------------- fused layer-3 aggregation + bias + residual + log_softmax ----------------
__global__ __launch_bounds__(256) void k_final(
    const float* __restrict__ p, const float* __restrict__ q,
    const int* __restrict__ offs, const int* __restrict__ ssrc,
    const float* __restrict__ bl3, float* __restrict__ out) {
    int wid = (blockIdx.x * 256 + threadIdx.x) >> 6;
    int lane = threadIdx.x & 63;
    if (wid >= NN) return;
    bool act = lane < NCLS;
    int beg = offs[wid], end = offs[wid + 1];
    float a0 = 0.f, a1 = 0.f;
    int i = beg;
    for (; i + 1 < end; i += 2) {
        int s0 = ssrc[i], s1 = ssrc[i + 1];
        a0 += act ? p[(size_t)s0 * NCLS + lane] : 0.f;
        a1 += act ? p[(size_t)s1 * NCLS + lane] : 0.f;
    }
    if (i < end) {
        int s0 = ssrc[i];
        a0 += act ? p[(size_t)s0 * NCLS + lane] : 0.f;
    }
    float inv = 1.f / fmaxf((float)(end - beg), 1.f);
    float v = act ? ((a0 + a1) * inv + bl3[lane] + q[(size_t)wid * NCLS + lane]) : -INFINITY;
    float m = v;
#pragma unroll
    for (int off = 32; off > 0; off >>= 1) m = fmaxf(m, __shfl_xor(m, off));
    float e = act ? expf(v - m) : 0.f;
    float s = e;
#pragma unroll
    for (int off = 32; off > 0; off >>= 1) s += __shfl_xor(s, off);
    float ls = logf(s);
    if (act) out[(size_t)wid * NCLS + lane] = v - m - ls;
}

extern "C" void kernel_launch(void* const* d_in, const int* in_sizes, int n_in,
                              void* d_out, int out_size, void* d_ws, size_t ws_size,
                              hipStream_t stream) {
    const float* x    = (const float*)d_in[0];
    const int*   ei   = (const int*)d_in[1];
    const int*   esrc = ei;        // row 0: src
    const int*   edst = ei + NE;   // row 1: dst
    const float* W_map = (const float*)d_in[2];
    const float* b_map = (const float*)d_in[3];
    const float* Wl1   = (const float*)d_in[4];
    const float* bl1   = (const float*)d_in[5];
    const float* Wr1   = (const float*)d_in[6];
    const float* Wl2   = (const float*)d_in[7];
    const float* bl2   = (const float*)d_in[8];
    const float* Wr2   = (const float*)d_in[9];
    const float* Wl3   = (const float*)d_in[10];
    const float* bl3   = (const float*)d_in[11];
    const float* Wr3   = (const float*)d_in[12];
    float* out = (float*)d_out;

    char* ws = (char*)d_ws;
    short* h0H = (short*)ws; ws += (size_t)NN * 128 * 2;
    short* h0L = (short*)ws; ws += (size_t)NN * 128 * 2;
    short* m0H = (short*)ws; ws += (size_t)NN * 128 * 2;
    short* m0L = (short*)ws; ws += (size_t)NN * 128 * 2;
    short* h1H = (short*)ws; ws += (size_t)NN * 128 * 2;
    short* h1L = (short*)ws; ws += (size_t)NN * 128 * 2;
    short* m1H = (short*)ws; ws += (size_t)NN * 128 * 2;
    short* m1L = (short*)ws; ws += (size_t)NN * 128 * 2;
    short* h2H = (short*)ws; ws += (size_t)NN * 256 * 2;
    short* h2L = (short*)ws; ws += (size_t)NN * 256 * 2;
    float* p   = (float*)ws; ws += (size_t)NN * NCLS * 4;
    float* q   = (float*)ws; ws += (size_t)NN * NCLS * 4;
    short* wt  = (short*)ws; ws += (size_t)368640 * 2;
    int* deg    = (int*)ws;  ws += (size_t)NN * 4;
    int* offs   = (int*)ws;  ws += (size_t)(NN + 2) * 4;
    int* cursor = (int*)ws;  ws += (size_t)NN * 4;
    int* ssrc   = (int*)ws;  ws += (size_t)NE * 4;
    int* bsum   = (int*)ws;  ws += (size_t)256 * 4;
    int* bpre   = (int*)ws;  ws += (size_t)256 * 4;

    // split-weight sub-buffers (offsets in shorts)
    short* m_h = wt + 0;      short* m_l = wt + 65536;   // [128][512]
    short* b1h = wt + 131072; short* b1l = wt + 163840;  // [128][256] = [Wr1;Wl1]
    short* b2h = wt + 196608; short* b2l = wt + 262144;  // [256][256] = [Wr2;Wl2]
    short* b3h = wt + 327680; short* b3l = wt + 348160;  // [80][256]  = [Wl3|Wr3]

    // --- weight split/transpose (tiny) ---
    k_wsplit<<<(128 * 512 + 255) / 256, 256, 0, stream>>>(W_map, m_h, m_l, FIN, 128, 512, 0, 9);
    k_wsplit<<<(128 * 128 + 255) / 256, 256, 0, stream>>>(Wr1, b1h, b1l, 128, 128, 256, 0, 7);
    k_wsplit<<<(128 * 128 + 255) / 256, 256, 0, stream>>>(Wl1, b1h, b1l, 128, 128, 256, 128, 7);
    k_wsplit<<<(256 * 128 + 255) / 256, 256, 0, stream>>>(Wr2, b2h, b2l, 128, 256, 256, 0, 7);
    k_wsplit<<<(256 * 128 + 255) / 256, 256, 0, stream>>>(Wl2, b2h, b2l, 128, 256, 256, 128, 7);
    k_wsplit<<<(40 * 256 + 255) / 256, 256, 0, stream>>>(Wl3, b3h, b3l, 256, 40, 256, 0, 8);
    k_wsplit<<<(40 * 256 + 255) / 256, 256, 0, stream>>>(Wr3, b3h + 40 * 256, b3l + 40 * 256, 256, 40, 256, 0, 8);

    // --- CSR bucketing of edges by dst (two-level scan) ---
    (void)hipMemsetAsync(deg, 0, (size_t)NN * 4, stream);
    k_count<<<(NE + 255) / 256, 256, 0, stream>>>(edst, deg);
    k_scan1<<<NB, 256, 0, stream>>>(deg, offs, bsum);
    k_scan2<<<1, 256, 0, stream>>>(bsum, bpre, offs);
    k_scan3<<<NB, 256, 0, stream>>>(offs, bpre, cursor);
    k_scatter<<<(NE + 255) / 256, 256, 0, stream>>>(esrc, edst, cursor, ssrc);

    const int g64 = (NN + 63) / 64;  // 782
    const int aggBlocks = (NN * 64) / 256;

    // h0 = x @ W_map + b_map -> h0H/h0L planes [NN][128]
    k_mm<64, 2, 2, true, false><<<dim3(g64, 2), 256, 0, stream>>>(
        (const void*)x, nullptr, nullptr, nullptr, 512, m_h, m_l, b_map,
        h0H, h0L, 128, nullptr, nullptr, 0, NN, 128, FIN, 512);

    // mean(h0) -> m0H/m0L
    k_aggb<<<aggBlocks, 256, 0, stream>>>(h0H, offs, ssrc, m0H, m0L);

    // h1 = relu([h0|mean] @ [Wr1;Wl1] + bl1) -> h1H/h1L
    k_mm<64, 2, 2, false, true><<<dim3(g64, 2), 256, 0, stream>>>(
        (const void*)h0H, (const void*)h0L, m0H, m0L, 128, b1h, b1l, bl1,
        h1H, h1L, 128, nullptr, nullptr, 0, NN, 128, 256, 256);

    // mean(h1) -> m1H/m1L
    k_aggb<<<aggBlocks, 256, 0, stream>>>(h1H, offs, ssrc, m1H, m1L);

    // h2 = relu([h1|mean] @ [Wr2;Wl2] + bl2) -> h2H/h2L [NN][256]
    k_mm<64, 2, 2, false, true><<<dim3(g64, 4), 256, 0, stream>>>(
        (const void*)h1H, (const void*)h1L, m1H, m1L, 128, b2h, b2l, bl2,
        h2H, h2L, 256, nullptr, nullptr, 0, NN, 256, 256, 256);

    // [p|q] = h2 @ [Wl3|Wr3]  (no bias; bl3 added in k_final)
    k_mm<80, 4, 1, false, false><<<dim3(g64, 1), 256, 0, stream>>>(
        (const void*)h2H, (const void*)h2L, nullptr, nullptr, 256, b3h, b3l, nullptr,
        nullptr, nullptr, 0, p, q, NCLS, NN, 80, 256, 256);

    // fused: logits = mean_agg(p) + bl3 + q; log_softmax -> out
    k_final<<<aggBlocks, 256, 0, stream>>>(p, q, offs, ssrc, bl3, out);
}

// Round 9
// 531.693 us; speedup vs baseline: 2.1740x; 1.0018x over previous
//
#include <hip/hip_runtime.h>
#include <math.h>

#define NN 50000
#define NE 800000
#define FIN 500
#define DH 128
#define D2H 256
#define NCLS 40
#define NB 196  // scan blocks = ceil(NN/256)

typedef short short8 __attribute__((ext_vector_type(8)));
typedef float f32x4 __attribute__((ext_vector_type(4)));

__device__ __forceinline__ unsigned short f2bf(float f) {
    unsigned u = __float_as_uint(f);
    unsigned r = (u + 0x7FFFu + ((u >> 16) & 1u)) >> 16;
    return (unsigned short)r;
}
__device__ __forceinline__ float bf2f(unsigned short h) {
    return __uint_as_float(((unsigned)h) << 16);
}

// ---- weight split+transpose: W[Ksrc][N] fp32 -> dst hi/lo [N][KpadTot] bf16 at col offset koff ----
__global__ void k_wsplit(const float* __restrict__ W, short* __restrict__ dh,
                         short* __restrict__ dl, int Ksrc, int N, int KpadTot,
                         int koff, int llog) {
    int i = blockIdx.x * 256 + threadIdx.x;
    int len = 1 << llog;
    if (i >= N * len) return;
    int n = i >> llog, kk = i & (len - 1);
    float v = (kk < Ksrc) ? W[(size_t)kk * N + n] : 0.f;
    unsigned short hi = f2bf(v);
    float lo = v - bf2f(hi);
    size_t di = (size_t)n * KpadTot + koff + kk;
    dh[di] = (short)hi;
    dl[di] = (short)f2bf(lo);
}

// ---------------- counting sort of edges by dst ----------------
__global__ void k_count(const int* __restrict__ dst, int* __restrict__ deg) {
    int e = blockIdx.x * blockDim.x + threadIdx.x;
    if (e < NE) atomicAdd(&deg[dst[e]], 1);
}

__global__ void k_scan1(const int* __restrict__ deg, int* __restrict__ offs,
                        int* __restrict__ bsum) {
    __shared__ int sm[256];
    int tid = threadIdx.x;
    int i = blockIdx.x * 256 + tid;
    int v = (i < NN) ? deg[i] : 0;
    sm[tid] = v;
    __syncthreads();
    for (int off = 1; off < 256; off <<= 1) {
        int t = (tid >= off) ? sm[tid - off] : 0;
        __syncthreads();
        sm[tid] += t;
        __syncthreads();
    }
    if (i < NN) offs[i] = sm[tid] - v;
    if (tid == 255) bsum[blockIdx.x] = sm[255];
}

__global__ void k_scan2(const int* __restrict__ bsum, int* __restrict__ bpre,
                        int* __restrict__ offs) {
    __shared__ int sm[256];
    int tid = threadIdx.x;
    int v = (tid < NB) ? bsum[tid] : 0;
    sm[tid] = v;
    __syncthreads();
    for (int off = 1; off < 256; off <<= 1) {
        int t = (tid >= off) ? sm[tid - off] : 0;
        __syncthreads();
        sm[tid] += t;
        __syncthreads();
    }
    if (tid < NB) bpre[tid] = sm[tid] - v;
    if (tid == 255) offs[NN] = sm[255];
}

__global__ void k_scan3(int* __restrict__ offs, const int* __restrict__ bpre,
                        int* __restrict__ cursor) {
    int i = blockIdx.x * 256 + threadIdx.x;
    if (i < NN) {
        int v = offs[i] + bpre[blockIdx.x];
        offs[i] = v;
        cursor[i] = v;
    }
}

__global__ void k_scatter(const int* __restrict__ src, const int* __restrict__ dst,
                          int* __restrict__ cursor, int* __restrict__ ssrc) {
    int e = blockIdx.x * blockDim.x + threadIdx.x;
    if (e < NE) {
        int p = atomicAdd(&cursor[dst[e]], 1);
        ssrc[p] = src[e];
    }
}

// ---- mean aggregation from bf16 table [NN][128] -> bf16 mean plane [NN][128] ----
// one wave per node; quarter-wave (16 lanes, short8=16B each) per edge; 4 edges/step, unroll 2
__global__ __launch_bounds__(256) void k_aggb(
    const short* __restrict__ hb, const int* __restrict__ offs,
    const int* __restrict__ ssrc, short* __restrict__ mH) {
    int wid = (blockIdx.x * 256 + threadIdx.x) >> 6;
    int lane = threadIdx.x & 63;
    if (wid >= NN) return;
    int sub = lane >> 4, l16 = lane & 15;
    int beg = offs[wid], end = offs[wid + 1];
    f32x4 a0 = {0.f, 0.f, 0.f, 0.f}, a1 = {0.f, 0.f, 0.f, 0.f};
    int i = beg + sub;
    for (; i + 4 < end; i += 8) {
        int s0 = ssrc[i];
        int s1 = ssrc[i + 4];
        short8 v0 = *(const short8*)(hb + (size_t)s0 * 128 + l16 * 8);
        short8 v1 = *(const short8*)(hb + (size_t)s1 * 128 + l16 * 8);
#pragma unroll
        for (int j = 0; j < 4; ++j) {
            a0[j] += bf2f((unsigned short)v0[j]) + bf2f((unsigned short)v1[j]);
            a1[j] += bf2f((unsigned short)v0[j + 4]) + bf2f((unsigned short)v1[j + 4]);
        }
    }
    if (i < end) {
        int s0 = ssrc[i];
        short8 v0 = *(const short8*)(hb + (size_t)s0 * 128 + l16 * 8);
#pragma unroll
        for (int j = 0; j < 4; ++j) {
            a0[j] += bf2f((unsigned short)v0[j]);
            a1[j] += bf2f((unsigned short)v0[j + 4]);
        }
    }
#pragma unroll
    for (int j = 0; j < 4; ++j) {
        a0[j] += __shfl_xor(a0[j], 16);
        a0[j] += __shfl_xor(a0[j], 32);
        a1[j] += __shfl_xor(a1[j], 16);
        a1[j] += __shfl_xor(a1[j], 32);
    }
    if (sub == 0) {
        float inv = 1.f / fmaxf((float)(end - beg), 1.f);
        a0 *= inv; a1 *= inv;
        short8 hv;
#pragma unroll
        for (int j = 0; j < 4; ++j) {
            hv[j] = (short)f2bf(a0[j]);
            hv[j + 4] = (short)f2bf(a1[j]);
        }
        *(short8*)(mH + (size_t)wid * 128 + l16 * 8) = hv;
    }
}

// ---------------- MFMA GEMM: bf16 activations x (hi/lo split weights) ----------------
// 128 threads (2 waves), TM=32 rows/block, BN cols/block.
// A: AFP32 ? fp32 [M,K] (bf16-rounded on stage) : two bf16 K-segments (seg0 KS0 wide).
// B: pre-split hi/lo [N][Kpad]. 2 MFMA per tile: ah*bh + ah*bl (W fp32-exact).
// Out: CH bf16 plane [M][ldc], or fp32 split F0/F1 at splitN.
template <int BN, bool AFP32, bool RELU>
__global__ __launch_bounds__(128, 6) void k_mm(
    const void* __restrict__ A0v, const short* __restrict__ A1, int KS0,
    const short* __restrict__ Bhg, const short* __restrict__ Blg,
    const float* __restrict__ bias,
    short* __restrict__ CH, int ldc,
    float* __restrict__ F0, float* __restrict__ F1, int splitN,
    int M, int N, int K, int Kpad) {
    constexpr int NT = BN / 16;             // col tiles per wave (NWN=1)
    constexpr int BU = (BN * 4 + 127) / 128;
    __shared__ short Ah[32][40];
    __shared__ short Bh[BN][40];
    __shared__ short Bl[BN][40];
    int tid = threadIdx.x;
    int wave = tid >> 6, lane = tid & 63;   // wave = wm (NWM=2)
    int quad = lane >> 4, l16 = lane & 15;
    int rowBase = blockIdx.x * 32, colBase = blockIdx.y * BN;

    f32x4 acc[NT];
#pragma unroll
    for (int n = 0; n < NT; ++n) acc[n] = (f32x4){0.f, 0.f, 0.f, 0.f};

    int4 ra0, rb0[BU], rb1[BU];
    f32x4 fa0, fa1;

    auto loadTile = [&](int k0) {
#pragma unroll
        for (int u = 0; u < BU; ++u) {
            int q = tid + u * 128;
            rb0[u] = (int4){0, 0, 0, 0};
            rb1[u] = (int4){0, 0, 0, 0};
            if (q < BN * 4) {
                int r = q >> 2, j = q & 3;
                int gc = colBase + r;
                if (gc < N) {
                    rb0[u] = *(const int4*)(Bhg + (size_t)gc * Kpad + k0 + j * 8);
                    rb1[u] = *(const int4*)(Blg + (size_t)gc * Kpad + k0 + j * 8);
                }
            }
        }
        if constexpr (AFP32) {
            const float* A = (const float*)A0v;
            fa0 = (f32x4){0.f, 0.f, 0.f, 0.f};
            fa1 = (f32x4){0.f, 0.f, 0.f, 0.f};
            int r0 = tid >> 3, c0 = (tid & 7) * 4;
            int gr0 = rowBase + r0;
            if (gr0 < M && (k0 + c0) < K) fa0 = *(const f32x4*)(A + (size_t)gr0 * K + k0 + c0);
            int q1 = tid + 128;
            int r1 = q1 >> 3, c1 = (q1 & 7) * 4;
            int gr1 = rowBase + r1;
            if (gr1 < M && (k0 + c1) < K) fa1 = *(const f32x4*)(A + (size_t)gr1 * K + k0 + c1);
        } else {
            int seg = (k0 >= KS0) ? 1 : 0;
            int segW = seg ? (K - KS0) : KS0;
            const short* ap = seg ? A1 : (const short*)A0v;
            int col = k0 - (seg ? KS0 : 0);
            int r = tid >> 2, j = tid & 3;
            int gr = rowBase + r;
            ra0 = (int4){0, 0, 0, 0};
            if (gr < M) ra0 = *(const int4*)(ap + (size_t)gr * segW + col + j * 8);
        }
    };
    auto storeTile = [&]() {
#pragma unroll
        for (int u = 0; u < BU; ++u) {
            int q = tid + u * 128;
            if (q < BN * 4) {
                int r = q >> 2, j = q & 3;
                *(int4*)&Bh[r][j * 8] = rb0[u];
                *(int4*)&Bl[r][j * 8] = rb1[u];
            }
        }
        if constexpr (AFP32) {
            short hh[4];
            int r0 = tid >> 3, c0 = (tid & 7) * 4;
#pragma unroll
            for (int j = 0; j < 4; ++j) hh[j] = (short)f2bf(fa0[j]);
            *(int2*)&Ah[r0][c0] = *(const int2*)hh;
            int q1 = tid + 128;
            int r1 = q1 >> 3, c1 = (q1 & 7) * 4;
#pragma unroll
            for (int j = 0; j < 4; ++j) hh[j] = (short)f2bf(fa1[j]);
            *(int2*)&Ah[r1][c1] = *(const int2*)hh;
        } else {
            int r = tid >> 2, j = tid & 3;
            *(int4*)&Ah[r][j * 8] = ra0;
        }
    };

    loadTile(0);
    for (int k0 = 0; k0 < Kpad; k0 += 32) {
        __syncthreads();
        storeTile();
        __syncthreads();
        if (k0 + 32 < Kpad) loadTile(k0 + 32);
        int r = wave * 16 + l16;
        short8 afh = *(const short8*)&Ah[r][quad * 8];
#pragma unroll
        for (int n = 0; n < NT; ++n) {
            int c = n * 16 + l16;
            short8 bh = *(const short8*)&Bh[c][quad * 8];
            short8 bl = *(const short8*)&Bl[c][quad * 8];
            acc[n] = __builtin_amdgcn_mfma_f32_16x16x32_bf16(afh, bh, acc[n], 0, 0, 0);
            acc[n] = __builtin_amdgcn_mfma_f32_16x16x32_bf16(afh, bl, acc[n], 0, 0, 0);
        }
    }
    // ---- epilogue: C-layout col=lane&15, row=quad*4+reg ----
    int gr0 = rowBase + wave * 16 + quad * 4;
#pragma unroll
    for (int n = 0; n < NT; ++n) {
        int gc = colBase + n * 16 + l16;
        if (gc >= N) continue;
        float b = bias ? bias[gc] : 0.f;
#pragma unroll
        for (int r = 0; r < 4; ++r) {
            int gr = gr0 + r;
            if (gr < M) {
                float v = acc[n][r] + b;
                if (RELU) v = fmaxf(v, 0.f);
                if (CH) CH[(size_t)gr * ldc + gc] = (short)f2bf(v);
                if (F0) {
                    if (gc < splitN) F0[(size_t)gr * splitN + gc] = v;
                    else             F1[(size_t)gr * (N - splitN) + (gc - splitN)] = v;
                }
            }
        }
    }
}

// ---------------- fused layer-3 aggregation + bias + residual + log_softmax ----------------
__global__ __launch_bounds__(256) void k_final(
    const float* __restrict__ p, const float* __restrict__ q,
    const int* __restrict__ offs, const int* __restrict__ ssrc,
    const float* __restrict__ bl3, float* __restrict__ out) {
    int wid = (blockIdx.x * 256 + threadIdx.x) >> 6;
    int lane = threadIdx.x & 63;
    if (wid >= NN) return;
    bool act = lane < NCLS;
    int beg = offs[wid], end = offs[wid + 1];
    float a0 = 0.f, a1 = 0.f;
    int i = beg;
    for (; i + 1 < end; i += 2) {
        int s0 = ssrc[i], s1 = ssrc[i + 1];
        a0 += act ? p[(size_t)s0 * NCLS + lane] : 0.f;
        a1 += act ? p[(size_t)s1 * NCLS + lane] : 0.f;
    }
    if (i < end) {
        int s0 = ssrc[i];
        a0 += act ? p[(size_t)s0 * NCLS + lane] : 0.f;
    }
    float inv = 1.f / fmaxf((float)(end - beg), 1.f);
    float v = act ? ((a0 + a1) * inv + bl3[lane] + q[(size_t)wid * NCLS + lane]) : -INFINITY;
    float m = v;
#pragma unroll
    for (int off = 32; off > 0; off >>= 1) m = fmaxf(m, __shfl_xor(m, off));
    float e = act ? expf(v - m) : 0.f;
    float s = e;
#pragma unroll
    for (int off = 32; off > 0; off >>= 1) s += __shfl_xor(s, off);
    float ls = logf(s);
    if (act) out[(size_t)wid * NCLS + lane] = v - m - ls;
}

extern "C" void kernel_launch(void* const* d_in, const int* in_sizes, int n_in,
                              void* d_out, int out_size, void* d_ws, size_t ws_size,
                              hipStream_t stream) {
    const float* x    = (const float*)d_in[0];
    const int*   ei   = (const int*)d_in[1];
    const int*   esrc = ei;        // row 0: src
    const int*   edst = ei + NE;   // row 1: dst
    const float* W_map = (const float*)d_in[2];
    const float* b_map = (const float*)d_in[3];
    const float* Wl1   = (const float*)d_in[4];
    const float* bl1   = (const float*)d_in[5];
    const float* Wr1   = (const float*)d_in[6];
    const float* Wl2   = (const float*)d_in[7];
    const float* bl2   = (const float*)d_in[8];
    const float* Wr2   = (const float*)d_in[9];
    const float* Wl3   = (const float*)d_in[10];
    const float* bl3   = (const float*)d_in[11];
    const float* Wr3   = (const float*)d_in[12];
    float* out = (float*)d_out;

    char* ws = (char*)d_ws;
    short* h0H = (short*)ws; ws += (size_t)NN * 128 * 2;
    short* m0H = (short*)ws; ws += (size_t)NN * 128 * 2;
    short* h1H = (short*)ws; ws += (size_t)NN * 128 * 2;
    short* m1H = (short*)ws; ws += (size_t)NN * 128 * 2;
    short* h2H = (short*)ws; ws += (size_t)NN * 256 * 2;
    float* p   = (float*)ws; ws += (size_t)NN * NCLS * 4;
    float* q   = (float*)ws; ws += (size_t)NN * NCLS * 4;
    short* wt  = (short*)ws; ws += (size_t)368640 * 2;
    int* deg    = (int*)ws;  ws += (size_t)NN * 4;
    int* offs   = (int*)ws;  ws += (size_t)(NN + 2) * 4;
    int* cursor = (int*)ws;  ws += (size_t)NN * 4;
    int* ssrc   = (int*)ws;  ws += (size_t)NE * 4;
    int* bsum   = (int*)ws;  ws += (size_t)256 * 4;
    int* bpre   = (int*)ws;  ws += (size_t)256 * 4;

    // split-weight sub-buffers (offsets in shorts)
    short* m_h = wt + 0;      short* m_l = wt + 65536;   // [128][512]
    short* b1h = wt + 131072; short* b1l = wt + 163840;  // [128][256] = [Wr1;Wl1]
    short* b2h = wt + 196608; short* b2l = wt + 262144;  // [256][256] = [Wr2;Wl2]
    short* b3h = wt + 327680; short* b3l = wt + 348160;  // [80][256]  = [Wl3|Wr3]

    // --- weight split/transpose (tiny) ---
    k_wsplit<<<(128 * 512 + 255) / 256, 256, 0, stream>>>(W_map, m_h, m_l, FIN, 128, 512, 0, 9);
    k_wsplit<<<(128 * 128 + 255) / 256, 256, 0, stream>>>(Wr1, b1h, b1l, 128, 128, 256, 0, 7);
    k_wsplit<<<(128 * 128 + 255) / 256, 256, 0, stream>>>(Wl1, b1h, b1l, 128, 128, 256, 128, 7);
    k_wsplit<<<(256 * 128 + 255) / 256, 256, 0, stream>>>(Wr2, b2h, b2l, 128, 256, 256, 0, 7);
    k_wsplit<<<(256 * 128 + 255) / 256, 256, 0, stream>>>(Wl2, b2h, b2l, 128, 256, 256, 128, 7);
    k_wsplit<<<(40 * 256 + 255) / 256, 256, 0, stream>>>(Wl3, b3h, b3l, 256, 40, 256, 0, 8);
    k_wsplit<<<(40 * 256 + 255) / 256, 256, 0, stream>>>(Wr3, b3h + 40 * 256, b3l + 40 * 256, 256, 40, 256, 0, 8);

    // --- CSR bucketing of edges by dst (two-level scan) ---
    (void)hipMemsetAsync(deg, 0, (size_t)NN * 4, stream);
    k_count<<<(NE + 255) / 256, 256, 0, stream>>>(edst, deg);
    k_scan1<<<NB, 256, 0, stream>>>(deg, offs, bsum);
    k_scan2<<<1, 256, 0, stream>>>(bsum, bpre, offs);
    k_scan3<<<NB, 256, 0, stream>>>(offs, bpre, cursor);
    k_scatter<<<(NE + 255) / 256, 256, 0, stream>>>(esrc, edst, cursor, ssrc);

    const int g32 = (NN + 31) / 32;  // 1563
    const int aggBlocks = (NN * 64) / 256;

    // h0 = x @ W_map + b_map -> h0H [NN][128] bf16
    k_mm<64, true, false><<<dim3(g32, 2), 128, 0, stream>>>(
        (const void*)x, nullptr, 512, m_h, m_l, b_map,
        h0H, 128, nullptr, nullptr, 0, NN, 128, FIN, 512);

    // mean(h0) -> m0H
    k_aggb<<<aggBlocks, 256, 0, stream>>>(h0H, offs, ssrc, m0H);

    // h1 = relu([h0|mean] @ [Wr1;Wl1] + bl1) -> h1H
    k_mm<64, false, true><<<dim3(g32, 2), 128, 0, stream>>>(
        (const void*)h0H, m0H, 128, b1h, b1l, bl1,
        h1H, 128, nullptr, nullptr, 0, NN, 128, 256, 256);

    // mean(h1) -> m1H
    k_aggb<<<aggBlocks, 256, 0, stream>>>(h1H, offs, ssrc, m1H);

    // h2 = relu([h1|mean] @ [Wr2;Wl2] + bl2) -> h2H [NN][256]
    k_mm<64, false, true><<<dim3(g32, 4), 128, 0, stream>>>(
        (const void*)h1H, m1H, 128, b2h, b2l, bl2,
        h2H, 256, nullptr, nullptr, 0, NN, 256, 256, 256);

    // [p|q] = h2 @ [Wl3|Wr3]  (no bias; bl3 added in k_final)
    k_mm<80, false, false><<<dim3(g32, 1), 128, 0, stream>>>(
        (const void*)h2H, nullptr, 256, b3h, b3l, nullptr,
        nullptr, 0, p, q, NCLS, NN, 80, 256, 256);

    // fused: logits = mean_agg(p) + bl3 + q; log_softmax -> out
    k_final<<<aggBlocks, 256, 0, stream>>>(p, q, offs, ssrc, bl3, out);
}